// Round 4
// baseline (478.914 us; speedup 1.0000x reference)
//
#include <hip/hip_runtime.h>
#include <math.h>

#define B_    2
#define L_    2048
#define D_    768
#define K_    12
#define KQ_   6
#define M_    4
#define H_    64
#define ZC_   780      // MEM + K
#define NTOK_ 4096     // B*L
#define NC_   64       // scan chunks per batch
#define LC_   32       // chunk length (L/NC)
#define QLN_  3264     // q (3072) + lat (192) fused N
#define QLP_  3328     // padded to 26*128

typedef __attribute__((ext_vector_type(8))) _Float16 half8;
typedef __attribute__((ext_vector_type(4))) float f32x4;

__device__ __forceinline__ float softplus_f(float x) {
  return (x > 20.f) ? x : log1pf(expf(x));
}

// async global->LDS 16B per lane (dest must be wave-uniform base + lane*16)
__device__ __forceinline__ void async16(const _Float16* g, _Float16* l) {
  __builtin_amdgcn_global_load_lds(
      (const __attribute__((address_space(1))) unsigned int*)g,
      (__attribute__((address_space(3))) unsigned int*)l, 16, 0, 0);
}

// ---------------------------------------------------------------------------
// Zero-init for split-K atomic targets (out: 4096x768, z_pre: 4096x780)
// ---------------------------------------------------------------------------
__global__ void zero2_kernel(float* __restrict__ a, size_t na,
                             float* __restrict__ b, size_t nb) {
  size_t i = (size_t)blockIdx.x * 256 + threadIdx.x;
  if (i < na) a[i] = 0.f;
  if (i < nb) b[i] = 0.f;
}

// ---------------------------------------------------------------------------
// Precompute theta / w_int tables (per k,h,m) and softplus(decay_slopes)
// ---------------------------------------------------------------------------
__global__ void precomp_kernel(const float* __restrict__ theta_d_raw,
                               const float* __restrict__ decay,
                               float* __restrict__ theta_tab,
                               float* __restrict__ w_tab,
                               float* __restrict__ slopes_sp) {
  int idx = blockIdx.x * 256 + threadIdx.x;   // (k*64+h) in [0,768)
  if (idx < K_) slopes_sp[idx] = softplus_f(decay[idx]);
  if (idx >= K_ * H_) return;
  float td[M_], ta[M_];
#pragma unroll
  for (int m = 0; m < M_; ++m) td[m] = softplus_f(theta_d_raw[idx * M_ + m]) + 1e-4f;
  ta[0] = td[0];
#pragma unroll
  for (int m = 1; m < M_; ++m) ta[m] = ta[m - 1] + td[m];
  float total = ta[M_ - 1];
  float rs = 2.999f / total;                  // (TH_MAX - TH_MIN) / total
#pragma unroll
  for (int m = 0; m < M_; ++m) theta_tab[idx * M_ + m] = 0.001f + ta[m] * rs;
  float d0 = (ta[1] - ta[0]) * rs;
  float d1 = (ta[2] - ta[1]) * rs;
  float d2 = (ta[3] - ta[2]) * rs;
  w_tab[idx * M_ + 0] = 0.5f * d0;
  w_tab[idx * M_ + 1] = 0.5f * (d0 + d1);
  w_tab[idx * M_ + 2] = 0.5f * (d1 + d2);
  w_tab[idx * M_ + 3] = 0.5f * d2;
}

// ---------------------------------------------------------------------------
// gatelin = x @ gate_W  (768x12).  One wave per token, gate_W in LDS.
// ---------------------------------------------------------------------------
__global__ __launch_bounds__(256) void gate_kernel(const float* __restrict__ x,
                                                   const float* __restrict__ gW,
                                                   float* __restrict__ gatelin) {
  __shared__ float gws[768 * 12];
  for (int i = threadIdx.x; i < 768 * 12; i += 256) gws[i] = gW[i];
  __syncthreads();
  const int wave = threadIdx.x >> 6, lane = threadIdx.x & 63;
  const int t = blockIdx.x * 4 + wave;
  const float* xt = x + (size_t)t * D_;
  float acc[12];
#pragma unroll
  for (int k = 0; k < 12; ++k) acc[k] = 0.f;
#pragma unroll
  for (int i = 0; i < 12; ++i) {
    float xv = xt[lane + 64 * i];
    const float* w = &gws[(lane + 64 * i) * 12];
#pragma unroll
    for (int k = 0; k < 12; ++k) acc[k] += xv * w[k];
  }
#pragma unroll
  for (int k = 0; k < 12; ++k) {
    acc[k] += __shfl_xor(acc[k], 32);
    acc[k] += __shfl_xor(acc[k], 16);
    acc[k] += __shfl_xor(acc[k], 8);
    acc[k] += __shfl_xor(acc[k], 4);
    acc[k] += __shfl_xor(acc[k], 2);
    acc[k] += __shfl_xor(acc[k], 1);
  }
  if (lane < 12) {
    float v = 0.f;
#pragma unroll
    for (int k = 0; k < 12; ++k)
      if (lane == k) v = acc[k];
    gatelin[(size_t)t * K_ + lane] = v;
  }
}

// ---------------------------------------------------------------------------
// f32 -> fp16 hi/lo split (element-wise), for A operands (x)
// ---------------------------------------------------------------------------
__global__ void cvt_split_kernel(const float* __restrict__ src,
                                 _Float16* __restrict__ h,
                                 _Float16* __restrict__ l, int n) {
  int gid = blockIdx.x * 256 + threadIdx.x;
  if (gid >= n) return;
  float v = src[gid];
  _Float16 hi = (_Float16)v;
  h[gid] = hi;
  l[gid] = (_Float16)(v - (float)hi);
}

// ---------------------------------------------------------------------------
// Tiled transpose + fp16 convert (+optional lo) with padding.
// ---------------------------------------------------------------------------
__global__ void cvt_t_kernel(const float* __restrict__ src, long sKstride, int srstride,
                             _Float16* __restrict__ h, _Float16* __restrict__ l,
                             long dKstride, int dstride, int doff,
                             int R, int Nact, int write_lo) {
  __shared__ float tile[32][33];
  const int kz = blockIdx.z;
  const float* s = src + (size_t)kz * sKstride;
  _Float16* dh = h + (size_t)kz * dKstride;
  _Float16* dl = l ? (l + (size_t)kz * dKstride) : nullptr;
  const int kb = blockIdx.x * 32;   // src-row (K) base
  const int nb = blockIdx.y * 32;   // src-col (N) base
  const int tx = threadIdx.x & 31, ty = threadIdx.x >> 5;  // 32 x 8
  for (int i = ty; i < 32; i += 8) {
    int kk = kb + i, n = nb + tx;
    tile[i][tx] = (kk < R && n < Nact) ? s[(size_t)kk * srstride + n] : 0.f;
  }
  __syncthreads();
  for (int i = ty; i < 32; i += 8) {
    int n = nb + i, kk = kb + tx;
    if (kk < R) {
      float v = tile[tx][i];
      _Float16 hi = (_Float16)v;
      size_t di = (size_t)n * dstride + doff + kk;
      dh[di] = hi;
      if (write_lo) dl[di] = (_Float16)(v - (float)hi);
    }
  }
}

// ---------------------------------------------------------------------------
// MFMA fp16 GEMM with async global->LDS staging.
// C[M x Nact] = A[M x Kd] @ Bt[Npad x Kd]^T. 128x128 tile, BK=32, 4 waves.
// NTERMS=1: plain fp16.  NTERMS=3: split hi/lo (hh + hl + lh).
// ATOMIC=1: blockIdx.z is a K-split index (gridDim.z splits); epilogue does
//           atomicAdd into pre-zeroed C.  ATOMIC=0: blockIdx.z is batch.
// ---------------------------------------------------------------------------
template <int NTERMS, int ATOMIC>
__global__ __launch_bounds__(256)
void mfma_gemm_kernel(const _Float16* __restrict__ Ah, const _Float16* __restrict__ Al,
                      const _Float16* __restrict__ Bh, const _Float16* __restrict__ Bl,
                      float* __restrict__ C,
                      int Kd, int Nact,
                      long strideA, long strideB, long strideC) {
  constexpr int NBUF = (NTERMS > 1) ? 2 : 1;
  __shared__ __align__(16) _Float16 sA[NBUF][128 * 32];
  __shared__ __align__(16) _Float16 sB[NBUF][128 * 32];
  int kz, kbeg, kend;
  if (ATOMIC) {
    kz = 0;
    int len = Kd / gridDim.z;
    kbeg = blockIdx.z * len;
    kend = kbeg + len;
  } else {
    kz = blockIdx.z;
    kbeg = 0;
    kend = Kd;
  }
  const _Float16* A0 = Ah + (size_t)kz * strideA;
  const _Float16* B0 = Bh + (size_t)kz * strideB;
  float* Cb = C + (size_t)kz * strideC;
  const int bm0 = blockIdx.y * 128;
  const int bn0 = blockIdx.x * 128;
  const int tid = threadIdx.x;
  const int wave = tid >> 6, lane = tid & 63;
  const int m16 = lane & 15, quad = lane >> 4;
  const int wr = (wave & 1) * 64, wc = (wave >> 1) * 64;

  f32x4 acc[4][4];
#pragma unroll
  for (int i = 0; i < 4; ++i)
#pragma unroll
    for (int j = 0; j < 4; ++j) acc[i][j] = (f32x4){0.f, 0.f, 0.f, 0.f};

  const int lin = tid * 8;          // per-thread 8 halfs (16 B)
  const int r0 = lin >> 5;          // 0..63
  const int c0 = lin & 31;

  for (int k0 = kbeg; k0 < kend; k0 += 32) {
    {
      const _Float16* gA = A0 + (size_t)(bm0 + r0) * Kd + (k0 + c0);
      async16(gA, &sA[0][lin]);
      async16(gA + (size_t)64 * Kd, &sA[0][lin + 2048]);
      const _Float16* gB = B0 + (size_t)(bn0 + r0) * Kd + (k0 + c0);
      async16(gB, &sB[0][lin]);
      async16(gB + (size_t)64 * Kd, &sB[0][lin + 2048]);
      if constexpr (NTERMS > 1) {
        const _Float16* gA1 = Al + (size_t)kz * strideA + (size_t)(bm0 + r0) * Kd + (k0 + c0);
        async16(gA1, &sA[1][lin]);
        async16(gA1 + (size_t)64 * Kd, &sA[1][lin + 2048]);
        const _Float16* gB1 = Bl + (size_t)kz * strideB + (size_t)(bn0 + r0) * Kd + (k0 + c0);
        async16(gB1, &sB[1][lin]);
        async16(gB1 + (size_t)64 * Kd, &sB[1][lin + 2048]);
      }
    }
    __syncthreads();
    half8 a0[4], b0[4];
#pragma unroll
    for (int i = 0; i < 4; ++i)
      a0[i] = *(const half8*)&sA[0][(wr + i * 16 + m16) * 32 + quad * 8];
#pragma unroll
    for (int j = 0; j < 4; ++j)
      b0[j] = *(const half8*)&sB[0][(wc + j * 16 + m16) * 32 + quad * 8];
    if constexpr (NTERMS == 1) {
#pragma unroll
      for (int i = 0; i < 4; ++i)
#pragma unroll
        for (int j = 0; j < 4; ++j)
          acc[i][j] = __builtin_amdgcn_mfma_f32_16x16x32_f16(a0[i], b0[j], acc[i][j], 0, 0, 0);
    } else {
      half8 a1[4], b1[4];
#pragma unroll
      for (int i = 0; i < 4; ++i)
        a1[i] = *(const half8*)&sA[1][(wr + i * 16 + m16) * 32 + quad * 8];
#pragma unroll
      for (int j = 0; j < 4; ++j)
        b1[j] = *(const half8*)&sB[1][(wc + j * 16 + m16) * 32 + quad * 8];
#pragma unroll
      for (int i = 0; i < 4; ++i)
#pragma unroll
        for (int j = 0; j < 4; ++j) {
          acc[i][j] = __builtin_amdgcn_mfma_f32_16x16x32_f16(a0[i], b0[j], acc[i][j], 0, 0, 0);
          acc[i][j] = __builtin_amdgcn_mfma_f32_16x16x32_f16(a0[i], b1[j], acc[i][j], 0, 0, 0);
          acc[i][j] = __builtin_amdgcn_mfma_f32_16x16x32_f16(a1[i], b0[j], acc[i][j], 0, 0, 0);
        }
    }
    __syncthreads();
  }
  // epilogue: C/D layout col=lane&15, row=quad*4+reg
#pragma unroll
  for (int i = 0; i < 4; ++i) {
    const int row0 = bm0 + wr + i * 16 + quad * 4;
#pragma unroll
    for (int j = 0; j < 4; ++j) {
      const int col = bn0 + wc + j * 16 + m16;
      if (col < Nact) {
#pragma unroll
        for (int r = 0; r < 4; ++r) {
          if (ATOMIC)
            atomicAdd(&Cb[(size_t)(row0 + r) * Nact + col], acc[i][j][r]);
          else
            Cb[(size_t)(row0 + r) * Nact + col] = acc[i][j][r];
        }
      }
    }
  }
}

// ---------------------------------------------------------------------------
// Depthwise causal conv (CK=4) along l, per channel
// ---------------------------------------------------------------------------
__global__ void conv_kernel(const float* __restrict__ z,
                            const float* __restrict__ ck,
                            float* __restrict__ zc) {
  size_t idx = (size_t)blockIdx.x * 256 + threadIdx.x;
  if (idx >= (size_t)NTOK_ * ZC_) return;
  int c = (int)(idx % ZC_);
  int t = (int)(idx / ZC_);
  int l = t % L_;
  float acc = 0.f;
#pragma unroll
  for (int w = 0; w < 4; ++w) {
    int lw = l - 3 + w;
    if (lw >= 0) acc += z[idx - (size_t)(3 - w) * ZC_] * ck[w * ZC_ + c];
  }
  zc[idx] = acc;
}

// ---------------------------------------------------------------------------
// Scan pass A: per-(b,k,chunk) partial sums of (den, num_re[256], num_im[256])
// ---------------------------------------------------------------------------
__global__ void pass_a_kernel(const float* __restrict__ zc,
                              const float* __restrict__ theta_tab,
                              const float* __restrict__ score_scale,
                              const float* __restrict__ tanh_scale,
                              const float* __restrict__ slopes_sp,
                              float* __restrict__ csums) {
  const int c = blockIdx.x, k = blockIdx.y, b = blockIdx.z;
  const int tid = threadIdx.x;
  const int m = tid & 3, h = tid >> 2;
  const float theta_v = theta_tab[(k * H_ + h) * M_ + m];
  const float ts = tanh_scale[k], ss = score_scale[k], slope = slopes_sp[k];
  float sre = 0.f, sim = 0.f, dacc = 0.f;
  for (int ll = 0; ll < LC_; ++ll) {
    int l = c * LC_ + ll;
    size_t t = (size_t)b * L_ + l;
    float kv = zc[t * ZC_ + k * H_ + h];
    float sraw = zc[t * ZC_ + 768 + k];
    float lp = fminf(fmaxf(ss * sraw, -20.f), 20.f);
    float pw = expf(lp - slope * (float)(L_ - 1 - l));
    float ph = tanhf(ts * kv) * theta_v;
    float kvp = kv * pw;
    sre += kvp * cosf(ph);
    sim += kvp * sinf(ph);
    dacc += pw;
  }
  size_t base = (((size_t)b * K_ + k) * NC_ + c) * 513;
  if (tid == 0) csums[base] = dacc;
  csums[base + 1 + h * 4 + m] = sre;
  csums[base + 1 + 256 + h * 4 + m] = sim;
}

// ---------------------------------------------------------------------------
// Scan pass B: exclusive prefix over chunks (parallel across components)
// ---------------------------------------------------------------------------
__global__ void pass_b_kernel(const float* __restrict__ csums,
                              float* __restrict__ cpre) {
  int bk = blockIdx.y;
  int comp = blockIdx.x * 64 + threadIdx.x;
  if (comp >= 513) return;
  float run = 0.f;
  size_t base = (size_t)bk * NC_ * 513 + comp;
  for (int c = 0; c < NC_; ++c) {
    cpre[base + (size_t)c * 513] = run;
    run += csums[base + (size_t)c * 513];
  }
}

// ---------------------------------------------------------------------------
// Scan pass C: replay with carried state, contract with q over M, apply
// ns*gate, and write fp16 directly into spec-A operand asp[k][t][0:128].
// ---------------------------------------------------------------------------
__global__ void pass_c_kernel(const float* __restrict__ zc,
                              const float* __restrict__ qlat,
                              const float* __restrict__ theta_tab,
                              const float* __restrict__ w_tab,
                              const float* __restrict__ score_scale,
                              const float* __restrict__ tanh_scale,
                              const float* __restrict__ slopes_sp,
                              const float* __restrict__ cpre,
                              const float* __restrict__ gatelin,
                              const float* __restrict__ gate_b,
                              const float* __restrict__ ns,
                              _Float16* __restrict__ asp) {
  const int c = blockIdx.x, k = blockIdx.y, b = blockIdx.z;
  const int tid = threadIdx.x;
  const int m = tid & 3, h = tid >> 2;
  size_t base = (((size_t)b * K_ + k) * NC_ + c) * 513;
  float den = cpre[base];
  float sre = cpre[base + 1 + h * 4 + m];
  float sim = cpre[base + 1 + 256 + h * 4 + m];
  const float theta_v = theta_tab[(k * H_ + h) * M_ + m];
  const float w = w_tab[(k * H_ + h) * M_ + m];
  const float ts = tanh_scale[k], ss = score_scale[k], slope = slopes_sp[k];
  const float nsv = ns[k * H_ + h];
  const float gb = gate_b[k];
  const int kq = k >> 1;   // NREP = 2
  for (int ll = 0; ll < LC_; ++ll) {
    int l = c * LC_ + ll;
    size_t t = (size_t)b * L_ + l;
    float kv = zc[t * ZC_ + k * H_ + h];
    float sraw = zc[t * ZC_ + 768 + k];
    float lp = fminf(fmaxf(ss * sraw, -20.f), 20.f);
    float pw = expf(lp - slope * (float)(L_ - 1 - l));
    float ph = tanhf(ts * kv) * theta_v;
    float kvp = kv * pw;
    sre += kvp * cosf(ph);
    sim += kvp * sinf(ph);
    den += pw;
    float inv = 1.f / fmaxf(den, 1e-4f);
    float s_re = sre * inv, s_im = sim * inv;
    size_t qb = t * QLN_ + (size_t)(((kq * H_ + h) * M_ + m) * 2);
    float qr = qlat[qb], qi = qlat[qb + 1];
    float tr = (s_re * qr + s_im * qi) * w;
    float ti = (s_im * qr - s_re * qi) * w;
    tr += __shfl_xor(tr, 1); tr += __shfl_xor(tr, 2);
    ti += __shfl_xor(ti, 1); ti += __shfl_xor(ti, 2);
    if (m == 0) {
      float g = 1.f / (1.f + expf(-(gatelin[t * K_ + k] + gb))) * nsv;
      size_t ab = ((size_t)k * NTOK_ + t) * 320;
      asp[ab + h] = (_Float16)(tr * g);
      asp[ab + 64 + h] = (_Float16)(ti * g);
    }
  }
}

// ---------------------------------------------------------------------------
// Fill spec-A lat columns: asp[k][t][128:320] = qlat[t][3072+j] * hs[k]
// ---------------------------------------------------------------------------
__global__ void aspec_lat_kernel(const float* __restrict__ qlat,
                                 const float* __restrict__ hs,
                                 _Float16* __restrict__ asp) {
  int gid = blockIdx.x * 256 + threadIdx.x;
  if (gid >= K_ * NTOK_ * 192) return;
  int j = gid % 192;
  int r = gid / 192;
  int t = r % NTOK_;
  int k = r / NTOK_;
  asp[((size_t)k * NTOK_ + t) * 320 + 128 + j] =
      (_Float16)(qlat[(size_t)t * QLN_ + 3072 + j] * hs[k]);
}

// ---------------------------------------------------------------------------
// val/gate silu epilogue: yfull[k][t][384] -> y_h[t][2304] (fp16)
// ---------------------------------------------------------------------------
__global__ void silu_kernel(const float* __restrict__ yfull,
                            _Float16* __restrict__ yh) {
  int gid = blockIdx.x * 256 + threadIdx.x;
  if (gid >= K_ * NTOK_ * 192) return;
  int n = gid % 192;
  int r = gid / 192;
  int t = r % NTOK_;
  int k = r / NTOK_;
  size_t base = ((size_t)k * NTOK_ + t) * 384 + n;
  float val = yfull[base];
  float g = yfull[base + 192];
  float s = g / (1.f + expf(-g));
  yh[(size_t)t * 2304 + k * 192 + n] = (_Float16)(val * s);
}

// ---------------------------------------------------------------------------
extern "C" void kernel_launch(void* const* d_in, const int* in_sizes, int n_in,
                              void* d_out, int out_size, void* d_ws, size_t ws_size,
                              hipStream_t stream) {
  const float* x            = (const float*)d_in[0];
  const float* W_mem        = (const float*)d_in[1];
  const float* conv_k       = (const float*)d_in[2];
  const float* W_q          = (const float*)d_in[3];
  const float* theta_d_raw  = (const float*)d_in[4];
  const float* decay_slopes = (const float*)d_in[5];
  const float* score_scale  = (const float*)d_in[6];
  const float* tanh_scale   = (const float*)d_in[7];
  const float* W_re         = (const float*)d_in[8];
  const float* W_im         = (const float*)d_in[9];
  const float* norm_scale   = (const float*)d_in[10];
  const float* gate_W       = (const float*)d_in[11];
  const float* gate_b       = (const float*)d_in[12];
  const float* skip_down_W  = (const float*)d_in[13];
  const float* skip_up_W    = (const float*)d_in[14];
  const float* highway_scale= (const float*)d_in[15];
  const float* out_W        = (const float*)d_in[16];
  float* out = (float*)d_out;
  float* ws = (float*)d_ws;

  // ---- f32 region ----
  float* theta_tab = ws;                                  // 3072
  float* w_tab     = theta_tab + 3072;                    // 3072
  float* slopes_sp = w_tab + 3072;                        // 16
  float* z_pre     = slopes_sp + 16;                      // 3,194,880
  float* zc        = z_pre + (size_t)NTOK_ * ZC_;         // 3,194,880
  float* qlat      = zc + (size_t)NTOK_ * ZC_;            // 13,369,344
  float* gatelin   = qlat + (size_t)NTOK_ * QLN_;         // 49,152
  float* csums     = gatelin + (size_t)NTOK_ * K_;        // 787,968
  float* cpre      = csums + (size_t)B_ * K_ * NC_ * 513; // 787,968
  _Float16* y_h    = (_Float16*)(cpre + (size_t)B_ * K_ * NC_ * 513);  // 9,437,184 halfs
  float* f32_end   = (float*)(y_h + (size_t)NTOK_ * 2304);

  // alias (lifetimes checked): yfull (spec GEMM out, 18,874,368 f32) reuses
  // z_pre+zc+qlat (19,759,104 f32); all three dead before spec GEMM runs.
  float* yfull = z_pre;

  // ---- fp16 region ----
  _Float16* fp = (_Float16*)f32_end;
  _Float16* x_h    = fp;                fp += (size_t)NTOK_ * D_;
  _Float16* x_l    = fp;                fp += (size_t)NTOK_ * D_;
  _Float16* wmem_h = fp;                fp += (size_t)896 * 768;
  _Float16* wmem_l = fp;                fp += (size_t)896 * 768;
  _Float16* qlb_h  = fp;                fp += (size_t)QLP_ * 768;   // [W_q^T | skd^T | 0pad]
  _Float16* outw_h = fp;                fp += (size_t)768 * 2304;
  _Float16* asp_h  = fp;                fp += (size_t)K_ * NTOK_ * 320;
  _Float16* bsp_h  = fp;                fp += (size_t)K_ * 384 * 320;

  // zero split-K atomic targets (out 3.1M, z_pre 3.2M floats)
  zero2_kernel<<<(int)((3194880 + 255) / 256), 256, 0, stream>>>(out, (size_t)NTOK_ * D_,
                                                                 z_pre, (size_t)NTOK_ * ZC_);
  precomp_kernel<<<3, 256, 0, stream>>>(theta_d_raw, decay_slopes, theta_tab, w_tab, slopes_sp);

  // conversions
  cvt_split_kernel<<<(NTOK_ * D_ + 255) / 256, 256, 0, stream>>>(x, x_h, x_l, NTOK_ * D_);
  cvt_t_kernel<<<dim3(24, 28, 1), 256, 0, stream>>>(W_mem, 0, ZC_, wmem_h, wmem_l, 0, 768, 0, 768, ZC_, 1);
  cvt_t_kernel<<<dim3(24, 96, 1), 256, 0, stream>>>(W_q, 0, 3072, qlb_h, nullptr, 0, 768, 0, 768, 3072, 0);
  cvt_t_kernel<<<dim3(24, 8, 1), 256, 0, stream>>>(skip_down_W, 0, 192, qlb_h + (size_t)3072 * 768, nullptr, 0, 768, 0, 768, 192, 0);
  cvt_t_kernel<<<dim3(72, 24, 1), 256, 0, stream>>>(out_W, 0, 768, outw_h, nullptr, 0, 2304, 0, 2304, 768, 0);
  cvt_t_kernel<<<dim3(2, 12, K_), 256, 0, stream>>>(W_re, 64L * 384, 384, bsp_h, nullptr, 384L * 320, 320, 0, 64, 384, 0);
  cvt_t_kernel<<<dim3(2, 12, K_), 256, 0, stream>>>(W_im, 64L * 384, 384, bsp_h, nullptr, 384L * 320, 320, 64, 64, 384, 0);
  cvt_t_kernel<<<dim3(6, 12, K_), 256, 0, stream>>>(skip_up_W, 384, 4608, bsp_h, nullptr, 384L * 320, 320, 128, 192, 384, 0);

  // z_pre += x @ W_mem  (split fp16, split-K=2, atomic)
  mfma_gemm_kernel<3, 1><<<dim3(7, 32, 2), 256, 0, stream>>>(x_h, x_l, wmem_h, wmem_l, z_pre, 768, ZC_, 0, 0, 0);
  conv_kernel<<<(int)(((size_t)NTOK_ * ZC_ + 255) / 256), 256, 0, stream>>>(z_pre, conv_k, zc);
  // qlat = x @ [W_q | skip_down]  (4096 x 3264)
  mfma_gemm_kernel<1, 0><<<dim3(26, 32, 1), 256, 0, stream>>>(x_h, x_h, qlb_h, qlb_h, qlat, 768, QLN_, 0, 0, 0);
  // gatelin = x @ gate_W (dedicated dot kernel)
  gate_kernel<<<NTOK_ / 4, 256, 0, stream>>>(x, gate_W, gatelin);

  // chunked scan (f32)
  pass_a_kernel<<<dim3(NC_, K_, B_), 256, 0, stream>>>(zc, theta_tab, score_scale, tanh_scale, slopes_sp, csums);
  pass_b_kernel<<<dim3(9, B_ * K_), 64, 0, stream>>>(csums, cpre);
  pass_c_kernel<<<dim3(NC_, K_, B_), 256, 0, stream>>>(zc, qlat, theta_tab, w_tab, score_scale, tanh_scale,
                                                       slopes_sp, cpre, gatelin, gate_b, norm_scale, asp_h);
  // lat columns of spec A
  aspec_lat_kernel<<<(K_ * NTOK_ * 192 + 255) / 256, 256, 0, stream>>>(qlat, highway_scale, asp_h);

  // batched spec GEMM -> yfull[k][t][384]
  mfma_gemm_kernel<1, 0><<<dim3(3, 32, K_), 256, 0, stream>>>(asp_h, asp_h, bsp_h, bsp_h, yfull, 320, 384,
                                                              (long)NTOK_ * 320, 384L * 320, (long)NTOK_ * 384);
  // silu epilogue -> y_h (fp16, 4096x2304)
  silu_kernel<<<(K_ * NTOK_ * 192 + 255) / 256, 256, 0, stream>>>(yfull, y_h);
  // out += y @ out_W  (split-K=4, atomic)
  mfma_gemm_kernel<1, 1><<<dim3(6, 32, 4), 256, 0, stream>>>(y_h, y_h, outw_h, outw_h, out, 2304, 768, 0, 0, 0);
}

// Round 5
// 437.905 us; speedup vs baseline: 1.0936x; 1.0936x over previous
//
#include <hip/hip_runtime.h>
#include <math.h>

#define B_    2
#define L_    2048
#define D_    768
#define K_    12
#define KQ_   6
#define M_    4
#define H_    64
#define ZC_   780      // MEM + K
#define NTOK_ 4096     // B*L
#define NC_   64       // scan chunks per batch
#define LC_   32       // chunk length (L/NC)
#define QLN_  3264     // q (3072) + lat (192) fused N
#define QLP_  3328     // padded to 26*128

typedef __attribute__((ext_vector_type(8))) _Float16 half8;
typedef __attribute__((ext_vector_type(4))) float f32x4;

__device__ __forceinline__ float softplus_f(float x) {
  return (x > 20.f) ? x : log1pf(expf(x));
}

__device__ __forceinline__ float fast_tanh(float x) {
  float xx = fminf(fmaxf(x, -10.f), 10.f);
  float e = __expf(2.f * xx);
  return (e - 1.f) / (e + 1.f);
}

// async global->LDS 16B per lane (dest must be wave-uniform base + lane*16)
__device__ __forceinline__ void async16(const _Float16* g, _Float16* l) {
  __builtin_amdgcn_global_load_lds(
      (const __attribute__((address_space(1))) unsigned int*)g,
      (__attribute__((address_space(3))) unsigned int*)l, 16, 0, 0);
}

// ---------------------------------------------------------------------------
// Zero-init for split-K atomic targets (out: 4096x768, z_pre: 4096x780)
// ---------------------------------------------------------------------------
__global__ void zero2_kernel(float* __restrict__ a, size_t na,
                             float* __restrict__ b, size_t nb) {
  size_t i = (size_t)blockIdx.x * 256 + threadIdx.x;
  if (i < na) a[i] = 0.f;
  if (i < nb) b[i] = 0.f;
}

// ---------------------------------------------------------------------------
// Precompute theta / w_int tables (per k,h,m) and softplus(decay_slopes)
// ---------------------------------------------------------------------------
__global__ void precomp_kernel(const float* __restrict__ theta_d_raw,
                               const float* __restrict__ decay,
                               float* __restrict__ theta_tab,
                               float* __restrict__ w_tab,
                               float* __restrict__ slopes_sp) {
  int idx = blockIdx.x * 256 + threadIdx.x;   // (k*64+h) in [0,768)
  if (idx < K_) slopes_sp[idx] = softplus_f(decay[idx]);
  if (idx >= K_ * H_) return;
  float td[M_], ta[M_];
#pragma unroll
  for (int m = 0; m < M_; ++m) td[m] = softplus_f(theta_d_raw[idx * M_ + m]) + 1e-4f;
  ta[0] = td[0];
#pragma unroll
  for (int m = 1; m < M_; ++m) ta[m] = ta[m - 1] + td[m];
  float total = ta[M_ - 1];
  float rs = 2.999f / total;                  // (TH_MAX - TH_MIN) / total
#pragma unroll
  for (int m = 0; m < M_; ++m) theta_tab[idx * M_ + m] = 0.001f + ta[m] * rs;
  float d0 = (ta[1] - ta[0]) * rs;
  float d1 = (ta[2] - ta[1]) * rs;
  float d2 = (ta[3] - ta[2]) * rs;
  w_tab[idx * M_ + 0] = 0.5f * d0;
  w_tab[idx * M_ + 1] = 0.5f * (d0 + d1);
  w_tab[idx * M_ + 2] = 0.5f * (d1 + d2);
  w_tab[idx * M_ + 3] = 0.5f * d2;
}

// ---------------------------------------------------------------------------
// gatelin = x @ gate_W  (768x12).  One wave per token, gate_W in LDS.
// ---------------------------------------------------------------------------
__global__ __launch_bounds__(256) void gate_kernel(const float* __restrict__ x,
                                                   const float* __restrict__ gW,
                                                   float* __restrict__ gatelin) {
  __shared__ float gws[768 * 12];
  for (int i = threadIdx.x; i < 768 * 12; i += 256) gws[i] = gW[i];
  __syncthreads();
  const int wave = threadIdx.x >> 6, lane = threadIdx.x & 63;
  const int t = blockIdx.x * 4 + wave;
  const float* xt = x + (size_t)t * D_;
  float acc[12];
#pragma unroll
  for (int k = 0; k < 12; ++k) acc[k] = 0.f;
#pragma unroll
  for (int i = 0; i < 12; ++i) {
    float xv = xt[lane + 64 * i];
    const float* w = &gws[(lane + 64 * i) * 12];
#pragma unroll
    for (int k = 0; k < 12; ++k) acc[k] += xv * w[k];
  }
#pragma unroll
  for (int k = 0; k < 12; ++k) {
    acc[k] += __shfl_xor(acc[k], 32);
    acc[k] += __shfl_xor(acc[k], 16);
    acc[k] += __shfl_xor(acc[k], 8);
    acc[k] += __shfl_xor(acc[k], 4);
    acc[k] += __shfl_xor(acc[k], 2);
    acc[k] += __shfl_xor(acc[k], 1);
  }
  if (lane < 12) {
    float v = 0.f;
#pragma unroll
    for (int k = 0; k < 12; ++k)
      if (lane == k) v = acc[k];
    gatelin[(size_t)t * K_ + lane] = v;
  }
}

// ---------------------------------------------------------------------------
// f32 -> fp16 hi/lo split (element-wise), for A operands (x)
// ---------------------------------------------------------------------------
__global__ void cvt_split_kernel(const float* __restrict__ src,
                                 _Float16* __restrict__ h,
                                 _Float16* __restrict__ l, int n) {
  int gid = blockIdx.x * 256 + threadIdx.x;
  if (gid >= n) return;
  float v = src[gid];
  _Float16 hi = (_Float16)v;
  h[gid] = hi;
  l[gid] = (_Float16)(v - (float)hi);
}

// ---------------------------------------------------------------------------
// Generic transpose+convert body (shared LDS tile passed in)
// ---------------------------------------------------------------------------
__device__ __forceinline__ void cvt_t_body(float (*tile)[33], int bx, int by, int kz,
                                           const float* src, long sKs, int srs,
                                           _Float16* dh, _Float16* dl,
                                           long dKs, int dst, int doff,
                                           int R, int Nact, bool wlo) {
  const float* s = src + (size_t)kz * sKs;
  _Float16* dhh = dh + (size_t)kz * dKs;
  _Float16* dll = dl ? (dl + (size_t)kz * dKs) : nullptr;
  const int kb = bx * 32;
  const int nb = by * 32;
  const int tx = threadIdx.x & 31, ty = threadIdx.x >> 5;
  for (int i = ty; i < 32; i += 8) {
    int kk = kb + i, n = nb + tx;
    tile[i][tx] = (kk < R && n < Nact) ? s[(size_t)kk * srs + n] : 0.f;
  }
  __syncthreads();
  for (int i = ty; i < 32; i += 8) {
    int n = nb + i, kk = kb + tx;
    if (kk < R) {
      float v = tile[tx][i];
      _Float16 hi = (_Float16)v;
      size_t di = (size_t)n * dst + doff + kk;
      dhh[di] = hi;
      if (wlo) dll[di] = (_Float16)(v - (float)hi);
    }
  }
}

// ---------------------------------------------------------------------------
// Merged weight conversion (all 7 transpose jobs in one 6336-block dispatch)
// ---------------------------------------------------------------------------
__global__ void cvtw_kernel(const float* __restrict__ W_mem, const float* __restrict__ W_q,
                            const float* __restrict__ skip_down_W, const float* __restrict__ out_W,
                            const float* __restrict__ W_re, const float* __restrict__ W_im,
                            const float* __restrict__ skip_up_W,
                            _Float16* __restrict__ wmem_h, _Float16* __restrict__ wmem_l,
                            _Float16* __restrict__ qlb_h, _Float16* __restrict__ outw_h,
                            _Float16* __restrict__ bsp_h) {
  __shared__ float tile[32][33];
  int b = blockIdx.x;
  if (b < 672) {           // W_mem -> wmem (hi+lo), grid 24x28
    cvt_t_body(tile, b % 24, b / 24, 0, W_mem, 0, ZC_, wmem_h, wmem_l, 0, 768, 0, 768, ZC_, true);
    return;
  }
  b -= 672;
  if (b < 2304) {          // W_q -> qlb rows [0,3072), grid 24x96
    cvt_t_body(tile, b % 24, b / 24, 0, W_q, 0, 3072, qlb_h, nullptr, 0, 768, 0, 768, 3072, false);
    return;
  }
  b -= 2304;
  if (b < 192) {           // skip_down -> qlb rows [3072,3328), grid 24x8
    cvt_t_body(tile, b % 24, b / 24, 0, skip_down_W, 0, 192, qlb_h + (size_t)3072 * 768, nullptr,
               0, 768, 0, 768, 192, false);
    return;
  }
  b -= 192;
  if (b < 1728) {          // out_W -> outw, grid 72x24
    cvt_t_body(tile, b % 72, b / 72, 0, out_W, 0, 768, outw_h, nullptr, 0, 2304, 0, 2304, 768, false);
    return;
  }
  b -= 1728;
  if (b < 288) {           // W_re -> bsp[k][n][0:64], grid 2x12x12
    cvt_t_body(tile, b % 2, (b / 2) % 12, b / 24, W_re, 64L * 384, 384, bsp_h, nullptr,
               384L * 320, 320, 0, 64, 384, false);
    return;
  }
  b -= 288;
  if (b < 288) {           // W_im -> bsp[k][n][64:128]
    cvt_t_body(tile, b % 2, (b / 2) % 12, b / 24, W_im, 64L * 384, 384, bsp_h, nullptr,
               384L * 320, 320, 64, 64, 384, false);
    return;
  }
  b -= 288;
  // skip_up slice -> bsp[k][n][128:320], grid 6x12x12
  cvt_t_body(tile, b % 6, (b / 6) % 12, b / 72, skip_up_W, 384, 4608, bsp_h, nullptr,
             384L * 320, 320, 128, 192, 384, false);
}

// ---------------------------------------------------------------------------
// MFMA fp16 GEMM, software-pipelined: double-buffered LDS, raw s_barrier +
// fine-grained s_waitcnt vmcnt(G) so prefetch loads stay in flight across the
// barrier (never vmcnt(0) except the final iteration).
// C[M x Nact] = A[M x Kd] @ Bt[Npad x Kd]^T. 128x128 tile, BK=32, 4 waves.
// NTERMS=1: plain fp16.  NTERMS=3: split hi/lo (hh + hl + lh).
// ATOMIC=1: blockIdx.z is a K-split index; epilogue atomicAdds into zeroed C.
// ---------------------------------------------------------------------------
template <int NTERMS, int ATOMIC>
__global__ __launch_bounds__(256)
void mfma_gemm_kernel(const _Float16* __restrict__ Ah, const _Float16* __restrict__ Al,
                      const _Float16* __restrict__ Bh, const _Float16* __restrict__ Bl,
                      float* __restrict__ C,
                      int Kd, int Nact,
                      long strideA, long strideB, long strideC) {
  constexpr int NT2 = (NTERMS > 1) ? 2 : 1;
  __shared__ __align__(16) _Float16 sA[2][NT2][128 * 32];
  __shared__ __align__(16) _Float16 sB[2][NT2][128 * 32];
  int kz, kbeg, kend;
  if (ATOMIC) {
    kz = 0;
    int len = Kd / gridDim.z;
    kbeg = blockIdx.z * len;
    kend = kbeg + len;
  } else {
    kz = blockIdx.z;
    kbeg = 0;
    kend = Kd;
  }
  const _Float16* A0 = Ah + (size_t)kz * strideA;
  const _Float16* B0 = Bh + (size_t)kz * strideB;
  const _Float16* A1 = (NTERMS > 1) ? (Al + (size_t)kz * strideA) : nullptr;
  const _Float16* B1 = (NTERMS > 1) ? (Bl + (size_t)kz * strideB) : nullptr;
  float* Cb = C + (size_t)kz * strideC;
  const int bm0 = blockIdx.y * 128;
  const int bn0 = blockIdx.x * 128;
  const int tid = threadIdx.x;
  const int wave = tid >> 6, lane = tid & 63;
  const int m16 = lane & 15, quad = lane >> 4;
  const int wr = (wave & 1) * 64, wc = (wave >> 1) * 64;

  f32x4 acc[4][4];
#pragma unroll
  for (int i = 0; i < 4; ++i)
#pragma unroll
    for (int j = 0; j < 4; ++j) acc[i][j] = (f32x4){0.f, 0.f, 0.f, 0.f};

  const int lin = tid * 8;          // per-thread 8 halfs (16 B)
  const int r0 = lin >> 5;          // 0..63
  const int c0 = lin & 31;

  auto stage = [&](int k0, int kb) {
    const _Float16* gA = A0 + (size_t)(bm0 + r0) * Kd + (k0 + c0);
    async16(gA, &sA[kb][0][lin]);
    async16(gA + (size_t)64 * Kd, &sA[kb][0][lin + 2048]);
    const _Float16* gB = B0 + (size_t)(bn0 + r0) * Kd + (k0 + c0);
    async16(gB, &sB[kb][0][lin]);
    async16(gB + (size_t)64 * Kd, &sB[kb][0][lin + 2048]);
    if constexpr (NTERMS > 1) {
      const _Float16* gA1 = A1 + (size_t)(bm0 + r0) * Kd + (k0 + c0);
      async16(gA1, &sA[kb][1][lin]);
      async16(gA1 + (size_t)64 * Kd, &sA[kb][1][lin + 2048]);
      const _Float16* gB1 = B1 + (size_t)(bn0 + r0) * Kd + (k0 + c0);
      async16(gB1, &sB[kb][1][lin]);
      async16(gB1 + (size_t)64 * Kd, &sB[kb][1][lin + 2048]);
    }
  };

  const int niter = (kend - kbeg) / 32;
  stage(kbeg, 0);
  if (niter > 1) stage(kbeg + 32, 1);

  for (int it = 0; it < niter; ++it) {
    // wait only for this iteration's group; keep next group in flight
    if (it == niter - 1)
      __builtin_amdgcn_s_waitcnt(0x0F70);                       // vmcnt(0)
    else
      __builtin_amdgcn_s_waitcnt(NTERMS > 1 ? 0x0F78 : 0x0F74); // vmcnt(8)/vmcnt(4)
    __builtin_amdgcn_s_barrier();
    asm volatile("" ::: "memory");
    const int kb = it & 1;
    half8 a0[4], b0[4];
#pragma unroll
    for (int i = 0; i < 4; ++i)
      a0[i] = *(const half8*)&sA[kb][0][(wr + i * 16 + m16) * 32 + quad * 8];
#pragma unroll
    for (int j = 0; j < 4; ++j)
      b0[j] = *(const half8*)&sB[kb][0][(wc + j * 16 + m16) * 32 + quad * 8];
    if constexpr (NTERMS == 1) {
#pragma unroll
      for (int i = 0; i < 4; ++i)
#pragma unroll
        for (int j = 0; j < 4; ++j)
          acc[i][j] = __builtin_amdgcn_mfma_f32_16x16x32_f16(a0[i], b0[j], acc[i][j], 0, 0, 0);
    } else {
      half8 a1[4], b1[4];
#pragma unroll
      for (int i = 0; i < 4; ++i)
        a1[i] = *(const half8*)&sA[kb][1][(wr + i * 16 + m16) * 32 + quad * 8];
#pragma unroll
      for (int j = 0; j < 4; ++j)
        b1[j] = *(const half8*)&sB[kb][1][(wc + j * 16 + m16) * 32 + quad * 8];
#pragma unroll
      for (int i = 0; i < 4; ++i)
#pragma unroll
        for (int j = 0; j < 4; ++j) {
          acc[i][j] = __builtin_amdgcn_mfma_f32_16x16x32_f16(a0[i], b0[j], acc[i][j], 0, 0, 0);
          acc[i][j] = __builtin_amdgcn_mfma_f32_16x16x32_f16(a0[i], b1[j], acc[i][j], 0, 0, 0);
          acc[i][j] = __builtin_amdgcn_mfma_f32_16x16x32_f16(a1[i], b0[j], acc[i][j], 0, 0, 0);
        }
    }
    asm volatile("" ::: "memory");
    __builtin_amdgcn_s_barrier();   // all waves done reading buf kb
    asm volatile("" ::: "memory");
    if (it + 2 < niter) stage(kbeg + (it + 2) * 32, kb);
  }
  // epilogue: C/D layout col=lane&15, row=quad*4+reg
#pragma unroll
  for (int i = 0; i < 4; ++i) {
    const int row0 = bm0 + wr + i * 16 + quad * 4;
#pragma unroll
    for (int j = 0; j < 4; ++j) {
      const int col = bn0 + wc + j * 16 + m16;
      if (col < Nact) {
#pragma unroll
        for (int r = 0; r < 4; ++r) {
          if (ATOMIC)
            atomicAdd(&Cb[(size_t)(row0 + r) * Nact + col], acc[i][j][r]);
          else
            Cb[(size_t)(row0 + r) * Nact + col] = acc[i][j][r];
        }
      }
    }
  }
}

// ---------------------------------------------------------------------------
// Depthwise causal conv (CK=4) along l, per channel
// ---------------------------------------------------------------------------
__global__ void conv_kernel(const float* __restrict__ z,
                            const float* __restrict__ ck,
                            float* __restrict__ zc) {
  size_t idx = (size_t)blockIdx.x * 256 + threadIdx.x;
  if (idx >= (size_t)NTOK_ * ZC_) return;
  int c = (int)(idx % ZC_);
  int t = (int)(idx / ZC_);
  int l = t % L_;
  float acc = 0.f;
#pragma unroll
  for (int w = 0; w < 4; ++w) {
    int lw = l - 3 + w;
    if (lw >= 0) acc += z[idx - (size_t)(3 - w) * ZC_] * ck[w * ZC_ + c];
  }
  zc[idx] = acc;
}

// ---------------------------------------------------------------------------
// Scan pass A: per-(b,k,chunk) partial sums of (den, num_re[256], num_im[256])
// ---------------------------------------------------------------------------
__global__ void pass_a_kernel(const float* __restrict__ zc,
                              const float* __restrict__ theta_tab,
                              const float* __restrict__ score_scale,
                              const float* __restrict__ tanh_scale,
                              const float* __restrict__ slopes_sp,
                              float* __restrict__ csums) {
  const int c = blockIdx.x, k = blockIdx.y, b = blockIdx.z;
  const int tid = threadIdx.x;
  const int m = tid & 3, h = tid >> 2;
  const float theta_v = theta_tab[(k * H_ + h) * M_ + m];
  const float ts = tanh_scale[k], ss = score_scale[k], slope = slopes_sp[k];
  float sre = 0.f, sim = 0.f, dacc = 0.f;
  for (int ll = 0; ll < LC_; ++ll) {
    int l = c * LC_ + ll;
    size_t t = (size_t)b * L_ + l;
    float kv = zc[t * ZC_ + k * H_ + h];
    float sraw = zc[t * ZC_ + 768 + k];
    float lp = fminf(fmaxf(ss * sraw, -20.f), 20.f);
    float pw = __expf(lp - slope * (float)(L_ - 1 - l));
    float ph = fast_tanh(ts * kv) * theta_v;
    float kvp = kv * pw;
    sre += kvp * __cosf(ph);
    sim += kvp * __sinf(ph);
    dacc += pw;
  }
  size_t base = (((size_t)b * K_ + k) * NC_ + c) * 513;
  if (tid == 0) csums[base] = dacc;
  csums[base + 1 + h * 4 + m] = sre;
  csums[base + 1 + 256 + h * 4 + m] = sim;
}

// ---------------------------------------------------------------------------
// Scan pass B: exclusive prefix over chunks (parallel across components)
// ---------------------------------------------------------------------------
__global__ void pass_b_kernel(const float* __restrict__ csums,
                              float* __restrict__ cpre) {
  int bk = blockIdx.y;
  int comp = blockIdx.x * 64 + threadIdx.x;
  if (comp >= 513) return;
  float run = 0.f;
  size_t base = (size_t)bk * NC_ * 513 + comp;
  for (int c = 0; c < NC_; ++c) {
    cpre[base + (size_t)c * 513] = run;
    run += csums[base + (size_t)c * 513];
  }
}

// ---------------------------------------------------------------------------
// Scan pass C: replay with carried state, contract with q over M, apply
// ns*gate, and write fp16 directly into spec-A operand asp[k][t][0:128].
// ---------------------------------------------------------------------------
__global__ void pass_c_kernel(const float* __restrict__ zc,
                              const float* __restrict__ qlat,
                              const float* __restrict__ theta_tab,
                              const float* __restrict__ w_tab,
                              const float* __restrict__ score_scale,
                              const float* __restrict__ tanh_scale,
                              const float* __restrict__ slopes_sp,
                              const float* __restrict__ cpre,
                              const float* __restrict__ gatelin,
                              const float* __restrict__ gate_b,
                              const float* __restrict__ ns,
                              _Float16* __restrict__ asp) {
  const int c = blockIdx.x, k = blockIdx.y, b = blockIdx.z;
  const int tid = threadIdx.x;
  const int m = tid & 3, h = tid >> 2;
  size_t base = (((size_t)b * K_ + k) * NC_ + c) * 513;
  float den = cpre[base];
  float sre = cpre[base + 1 + h * 4 + m];
  float sim = cpre[base + 1 + 256 + h * 4 + m];
  const float theta_v = theta_tab[(k * H_ + h) * M_ + m];
  const float w = w_tab[(k * H_ + h) * M_ + m];
  const float ts = tanh_scale[k], ss = score_scale[k], slope = slopes_sp[k];
  const float nsv = ns[k * H_ + h];
  const float gb = gate_b[k];
  const int kq = k >> 1;   // NREP = 2
  for (int ll = 0; ll < LC_; ++ll) {
    int l = c * LC_ + ll;
    size_t t = (size_t)b * L_ + l;
    float kv = zc[t * ZC_ + k * H_ + h];
    float sraw = zc[t * ZC_ + 768 + k];
    float lp = fminf(fmaxf(ss * sraw, -20.f), 20.f);
    float pw = __expf(lp - slope * (float)(L_ - 1 - l));
    float ph = fast_tanh(ts * kv) * theta_v;
    float kvp = kv * pw;
    sre += kvp * __cosf(ph);
    sim += kvp * __sinf(ph);
    den += pw;
    float inv = 1.f / fmaxf(den, 1e-4f);
    float s_re = sre * inv, s_im = sim * inv;
    size_t qb = t * QLN_ + (size_t)(((kq * H_ + h) * M_ + m) * 2);
    float qr = qlat[qb], qi = qlat[qb + 1];
    float tr = (s_re * qr + s_im * qi) * w;
    float ti = (s_im * qr - s_re * qi) * w;
    tr += __shfl_xor(tr, 1); tr += __shfl_xor(tr, 2);
    ti += __shfl_xor(ti, 1); ti += __shfl_xor(ti, 2);
    if (m == 0) {
      float g = 1.f / (1.f + __expf(-(gatelin[t * K_ + k] + gb))) * nsv;
      size_t ab = ((size_t)k * NTOK_ + t) * 320;
      asp[ab + h] = (_Float16)(tr * g);
      asp[ab + 64 + h] = (_Float16)(ti * g);
    }
  }
}

// ---------------------------------------------------------------------------
// Fill spec-A lat columns: asp[k][t][128:320] = qlat[t][3072+j] * hs[k]
// ---------------------------------------------------------------------------
__global__ void aspec_lat_kernel(const float* __restrict__ qlat,
                                 const float* __restrict__ hs,
                                 _Float16* __restrict__ asp) {
  int gid = blockIdx.x * 256 + threadIdx.x;
  if (gid >= K_ * NTOK_ * 192) return;
  int j = gid % 192;
  int r = gid / 192;
  int t = r % NTOK_;
  int k = r / NTOK_;
  asp[((size_t)k * NTOK_ + t) * 320 + 128 + j] =
      (_Float16)(qlat[(size_t)t * QLN_ + 3072 + j] * hs[k]);
}

// ---------------------------------------------------------------------------
// val/gate silu epilogue: yfull[k][t][384] -> y_h[t][2304] (fp16)
// ---------------------------------------------------------------------------
__global__ void silu_kernel(const float* __restrict__ yfull,
                            _Float16* __restrict__ yh) {
  int gid = blockIdx.x * 256 + threadIdx.x;
  if (gid >= K_ * NTOK_ * 192) return;
  int n = gid % 192;
  int r = gid / 192;
  int t = r % NTOK_;
  int k = r / NTOK_;
  size_t base = ((size_t)k * NTOK_ + t) * 384 + n;
  float val = yfull[base];
  float g = yfull[base + 192];
  float s = g / (1.f + __expf(-g));
  yh[(size_t)t * 2304 + k * 192 + n] = (_Float16)(val * s);
}

// ---------------------------------------------------------------------------
extern "C" void kernel_launch(void* const* d_in, const int* in_sizes, int n_in,
                              void* d_out, int out_size, void* d_ws, size_t ws_size,
                              hipStream_t stream) {
  const float* x            = (const float*)d_in[0];
  const float* W_mem        = (const float*)d_in[1];
  const float* conv_k       = (const float*)d_in[2];
  const float* W_q          = (const float*)d_in[3];
  const float* theta_d_raw  = (const float*)d_in[4];
  const float* decay_slopes = (const float*)d_in[5];
  const float* score_scale  = (const float*)d_in[6];
  const float* tanh_scale   = (const float*)d_in[7];
  const float* W_re         = (const float*)d_in[8];
  const float* W_im         = (const float*)d_in[9];
  const float* norm_scale   = (const float*)d_in[10];
  const float* gate_W       = (const float*)d_in[11];
  const float* gate_b       = (const float*)d_in[12];
  const float* skip_down_W  = (const float*)d_in[13];
  const float* skip_up_W    = (const float*)d_in[14];
  const float* highway_scale= (const float*)d_in[15];
  const float* out_W        = (const float*)d_in[16];
  float* out = (float*)d_out;
  float* ws = (float*)d_ws;

  // ---- f32 region ----
  float* theta_tab = ws;                                  // 3072
  float* w_tab     = theta_tab + 3072;                    // 3072
  float* slopes_sp = w_tab + 3072;                        // 16
  float* z_pre     = slopes_sp + 16;                      // 3,194,880
  float* zc        = z_pre + (size_t)NTOK_ * ZC_;         // 3,194,880
  float* qlat      = zc + (size_t)NTOK_ * ZC_;            // 13,369,344
  float* gatelin   = qlat + (size_t)NTOK_ * QLN_;         // 49,152
  float* csums     = gatelin + (size_t)NTOK_ * K_;        // 787,968
  float* cpre      = csums + (size_t)B_ * K_ * NC_ * 513; // 787,968
  _Float16* y_h    = (_Float16*)(cpre + (size_t)B_ * K_ * NC_ * 513);  // 9,437,184 halfs
  float* f32_end   = (float*)(y_h + (size_t)NTOK_ * 2304);

  // alias (lifetimes checked): yfull (spec GEMM out, 18,874,368 f32) reuses
  // z_pre+zc+qlat (19,759,104 f32); all three dead before spec GEMM runs.
  float* yfull = z_pre;

  // ---- fp16 region ----
  _Float16* fp = (_Float16*)f32_end;
  _Float16* x_h    = fp;                fp += (size_t)NTOK_ * D_;
  _Float16* x_l    = fp;                fp += (size_t)NTOK_ * D_;
  _Float16* wmem_h = fp;                fp += (size_t)896 * 768;
  _Float16* wmem_l = fp;                fp += (size_t)896 * 768;
  _Float16* qlb_h  = fp;                fp += (size_t)QLP_ * 768;   // [W_q^T | skd^T | 0pad]
  _Float16* outw_h = fp;                fp += (size_t)768 * 2304;
  _Float16* asp_h  = fp;                fp += (size_t)K_ * NTOK_ * 320;
  _Float16* bsp_h  = fp;                fp += (size_t)K_ * 384 * 320;

  // zero split-K atomic targets (out 3.1M, z_pre 3.2M floats)
  zero2_kernel<<<(int)((3194880 + 255) / 256), 256, 0, stream>>>(out, (size_t)NTOK_ * D_,
                                                                 z_pre, (size_t)NTOK_ * ZC_);
  precomp_kernel<<<3, 256, 0, stream>>>(theta_d_raw, decay_slopes, theta_tab, w_tab, slopes_sp);

  // conversions
  cvt_split_kernel<<<(NTOK_ * D_ + 255) / 256, 256, 0, stream>>>(x, x_h, x_l, NTOK_ * D_);
  cvtw_kernel<<<6336, 256, 0, stream>>>(W_mem, W_q, skip_down_W, out_W, W_re, W_im, skip_up_W,
                                        wmem_h, wmem_l, qlb_h, outw_h, bsp_h);

  // z_pre += x @ W_mem  (split fp16, split-K=2, atomic)
  mfma_gemm_kernel<3, 1><<<dim3(7, 32, 2), 256, 0, stream>>>(x_h, x_l, wmem_h, wmem_l, z_pre, 768, ZC_, 0, 0, 0);
  conv_kernel<<<(int)(((size_t)NTOK_ * ZC_ + 255) / 256), 256, 0, stream>>>(z_pre, conv_k, zc);
  // qlat = x @ [W_q | skip_down]  (4096 x 3264)
  mfma_gemm_kernel<1, 0><<<dim3(26, 32, 1), 256, 0, stream>>>(x_h, x_h, qlb_h, qlb_h, qlat, 768, QLN_, 0, 0, 0);
  // gatelin = x @ gate_W (dedicated dot kernel)
  gate_kernel<<<NTOK_ / 4, 256, 0, stream>>>(x, gate_W, gatelin);

  // chunked scan (f32)
  pass_a_kernel<<<dim3(NC_, K_, B_), 256, 0, stream>>>(zc, theta_tab, score_scale, tanh_scale, slopes_sp, csums);
  pass_b_kernel<<<dim3(9, B_ * K_), 64, 0, stream>>>(csums, cpre);
  pass_c_kernel<<<dim3(NC_, K_, B_), 256, 0, stream>>>(zc, qlat, theta_tab, w_tab, score_scale, tanh_scale,
                                                       slopes_sp, cpre, gatelin, gate_b, norm_scale, asp_h);
  // lat columns of spec A
  aspec_lat_kernel<<<(K_ * NTOK_ * 192 + 255) / 256, 256, 0, stream>>>(qlat, highway_scale, asp_h);

  // batched spec GEMM -> yfull[k][t][384]
  mfma_gemm_kernel<1, 0><<<dim3(3, 32, K_), 256, 0, stream>>>(asp_h, asp_h, bsp_h, bsp_h, yfull, 320, 384,
                                                              (long)NTOK_ * 320, 384L * 320, (long)NTOK_ * 384);
  // silu epilogue -> y_h (fp16, 4096x2304)
  silu_kernel<<<(K_ * NTOK_ * 192 + 255) / 256, 256, 0, stream>>>(yfull, y_h);
  // out += y @ out_W  (split-K=4, atomic)
  mfma_gemm_kernel<1, 1><<<dim3(6, 32, 4), 256, 0, stream>>>(y_h, y_h, outw_h, outw_h, out, 2304, 768, 0, 0, 0);
}

// Round 7
// 418.000 us; speedup vs baseline: 1.1457x; 1.0476x over previous
//
#include <hip/hip_runtime.h>
#include <math.h>

#define B_    2
#define L_    2048
#define D_    768
#define K_    12
#define KQ_   6
#define M_    4
#define H_    64
#define ZC_   780      // MEM + K
#define NTOK_ 4096     // B*L
#define NC_   64       // scan chunks per batch
#define LC_   32       // chunk length (L/NC)
#define QLN_  3264     // q (3072) + lat (192) fused N
#define QLP_  3328     // padded to 26*128

typedef __attribute__((ext_vector_type(8))) _Float16 half8;
typedef __attribute__((ext_vector_type(4))) float f32x4;

__device__ __forceinline__ float softplus_f(float x) {
  return (x > 20.f) ? x : log1pf(expf(x));
}

__device__ __forceinline__ float fast_tanh(float x) {
  float xx = fminf(fmaxf(x, -10.f), 10.f);
  float e = __expf(2.f * xx);
  return (e - 1.f) / (e + 1.f);
}

// async global->LDS 16B per lane (dest = wave-uniform base + lane*16)
__device__ __forceinline__ void async16(const _Float16* g, _Float16* l) {
  __builtin_amdgcn_global_load_lds(
      (const __attribute__((address_space(1))) unsigned int*)g,
      (__attribute__((address_space(3))) unsigned int*)l, 16, 0, 0);
}

// val/gate 16-interleave permutation for spec-B columns:
// val j   -> (j/16)*32 + (j%16)
// gate j  -> (j/16)*32 + 16 + (j%16)
__device__ __forceinline__ int permcol(int n) {
  int isg = (n >= 192) ? 1 : 0;
  int j = n - 192 * isg;
  return (j >> 4) * 32 + (isg << 4) + (j & 15);
}

// ---------------------------------------------------------------------------
// Zero-init for split-K atomic targets
// ---------------------------------------------------------------------------
__global__ void zero2_kernel(float* __restrict__ a, size_t na,
                             float* __restrict__ b, size_t nb) {
  size_t i = (size_t)blockIdx.x * 256 + threadIdx.x;
  if (i < na) a[i] = 0.f;
  if (i < nb) b[i] = 0.f;
}

// ---------------------------------------------------------------------------
// Precompute theta / w_int tables (per k,h,m) and softplus(decay_slopes)
// ---------------------------------------------------------------------------
__global__ void precomp_kernel(const float* __restrict__ theta_d_raw,
                               const float* __restrict__ decay,
                               float* __restrict__ theta_tab,
                               float* __restrict__ w_tab,
                               float* __restrict__ slopes_sp) {
  int idx = blockIdx.x * 256 + threadIdx.x;
  if (idx < K_) slopes_sp[idx] = softplus_f(decay[idx]);
  if (idx >= K_ * H_) return;
  float td[M_], ta[M_];
#pragma unroll
  for (int m = 0; m < M_; ++m) td[m] = softplus_f(theta_d_raw[idx * M_ + m]) + 1e-4f;
  ta[0] = td[0];
#pragma unroll
  for (int m = 1; m < M_; ++m) ta[m] = ta[m - 1] + td[m];
  float total = ta[M_ - 1];
  float rs = 2.999f / total;
#pragma unroll
  for (int m = 0; m < M_; ++m) theta_tab[idx * M_ + m] = 0.001f + ta[m] * rs;
  float d0 = (ta[1] - ta[0]) * rs;
  float d1 = (ta[2] - ta[1]) * rs;
  float d2 = (ta[3] - ta[2]) * rs;
  w_tab[idx * M_ + 0] = 0.5f * d0;
  w_tab[idx * M_ + 1] = 0.5f * (d0 + d1);
  w_tab[idx * M_ + 2] = 0.5f * (d1 + d2);
  w_tab[idx * M_ + 3] = 0.5f * d2;
}

// ---------------------------------------------------------------------------
// gatelin = x @ gate_W  (768x12).  One wave per token, gate_W in LDS.
// ---------------------------------------------------------------------------
__global__ __launch_bounds__(256) void gate_kernel(const float* __restrict__ x,
                                                   const float* __restrict__ gW,
                                                   float* __restrict__ gatelin) {
  __shared__ float gws[768 * 12];
  for (int i = threadIdx.x; i < 768 * 12; i += 256) gws[i] = gW[i];
  __syncthreads();
  const int wave = threadIdx.x >> 6, lane = threadIdx.x & 63;
  const int t = blockIdx.x * 4 + wave;
  const float* xt = x + (size_t)t * D_;
  float acc[12];
#pragma unroll
  for (int k = 0; k < 12; ++k) acc[k] = 0.f;
#pragma unroll
  for (int i = 0; i < 12; ++i) {
    float xv = xt[lane + 64 * i];
    const float* w = &gws[(lane + 64 * i) * 12];
#pragma unroll
    for (int k = 0; k < 12; ++k) acc[k] += xv * w[k];
  }
#pragma unroll
  for (int k = 0; k < 12; ++k) {
    acc[k] += __shfl_xor(acc[k], 32);
    acc[k] += __shfl_xor(acc[k], 16);
    acc[k] += __shfl_xor(acc[k], 8);
    acc[k] += __shfl_xor(acc[k], 4);
    acc[k] += __shfl_xor(acc[k], 2);
    acc[k] += __shfl_xor(acc[k], 1);
  }
  if (lane < 12) {
    float v = 0.f;
#pragma unroll
    for (int k = 0; k < 12; ++k)
      if (lane == k) v = acc[k];
    gatelin[(size_t)t * K_ + lane] = v;
  }
}

// ---------------------------------------------------------------------------
// f32 -> fp16 hi/lo split
// ---------------------------------------------------------------------------
__global__ void cvt_split_kernel(const float* __restrict__ src,
                                 _Float16* __restrict__ h,
                                 _Float16* __restrict__ l, int n) {
  int gid = blockIdx.x * 256 + threadIdx.x;
  if (gid >= n) return;
  float v = src[gid];
  _Float16 hi = (_Float16)v;
  h[gid] = hi;
  l[gid] = (_Float16)(v - (float)hi);
}

// ---------------------------------------------------------------------------
// Transpose+convert body; optional val/gate column permutation (perm)
// ---------------------------------------------------------------------------
__device__ __forceinline__ void cvt_t_body(float (*tile)[33], int bx, int by, int kz,
                                           const float* src, long sKs, int srs,
                                           _Float16* dh, _Float16* dl,
                                           long dKs, int dst, int doff,
                                           int R, int Nact, bool wlo, bool perm) {
  const float* s = src + (size_t)kz * sKs;
  _Float16* dhh = dh + (size_t)kz * dKs;
  _Float16* dll = dl ? (dl + (size_t)kz * dKs) : nullptr;
  const int kb = bx * 32;
  const int nb = by * 32;
  const int tx = threadIdx.x & 31, ty = threadIdx.x >> 5;
  for (int i = ty; i < 32; i += 8) {
    int kk = kb + i, n = nb + tx;
    tile[i][tx] = (kk < R && n < Nact) ? s[(size_t)kk * srs + n] : 0.f;
  }
  __syncthreads();
  for (int i = ty; i < 32; i += 8) {
    int n = nb + i, kk = kb + tx;
    if (kk < R) {
      float v = tile[tx][i];
      _Float16 hi = (_Float16)v;
      int dn = perm ? permcol(n) : n;
      size_t di = (size_t)dn * dst + doff + kk;
      dhh[di] = hi;
      if (wlo) dll[di] = (_Float16)(v - (float)hi);
    }
  }
}

// ---------------------------------------------------------------------------
// Merged weight conversion (all transpose jobs, one dispatch)
// ---------------------------------------------------------------------------
__global__ void cvtw_kernel(const float* __restrict__ W_mem, const float* __restrict__ W_q,
                            const float* __restrict__ skip_down_W, const float* __restrict__ out_W,
                            const float* __restrict__ W_re, const float* __restrict__ W_im,
                            const float* __restrict__ skip_up_W,
                            _Float16* __restrict__ wmem_h, _Float16* __restrict__ wmem_l,
                            _Float16* __restrict__ qlb_h, _Float16* __restrict__ outw_h,
                            _Float16* __restrict__ bsp_h) {
  __shared__ float tile[32][33];
  int b = blockIdx.x;
  if (b < 672) {           // W_mem -> wmem (hi+lo), 24x28
    cvt_t_body(tile, b % 24, b / 24, 0, W_mem, 0, ZC_, wmem_h, wmem_l, 0, 768, 0, 768, ZC_, true, false);
    return;
  }
  b -= 672;
  if (b < 2304) {          // W_q -> qlb rows [0,3072), 24x96
    cvt_t_body(tile, b % 24, b / 24, 0, W_q, 0, 3072, qlb_h, nullptr, 0, 768, 0, 768, 3072, false, false);
    return;
  }
  b -= 2304;
  if (b < 192) {           // skip_down -> qlb rows [3072,3328), 24x8
    cvt_t_body(tile, b % 24, b / 24, 0, skip_down_W, 0, 192, qlb_h + (size_t)3072 * 768, nullptr,
               0, 768, 0, 768, 192, false, false);
    return;
  }
  b -= 192;
  if (b < 1728) {          // out_W -> outw, 72x24
    cvt_t_body(tile, b % 72, b / 72, 0, out_W, 0, 768, outw_h, nullptr, 0, 2304, 0, 2304, 768, false, false);
    return;
  }
  b -= 1728;
  if (b < 288) {           // W_re -> bsp[k][perm(n)][0:64], 2x12x12
    cvt_t_body(tile, b % 2, (b / 2) % 12, b / 24, W_re, 64L * 384, 384, bsp_h, nullptr,
               384L * 320, 320, 0, 64, 384, false, true);
    return;
  }
  b -= 288;
  if (b < 288) {           // W_im -> bsp[k][perm(n)][64:128]
    cvt_t_body(tile, b % 2, (b / 2) % 12, b / 24, W_im, 64L * 384, 384, bsp_h, nullptr,
               384L * 320, 320, 64, 64, 384, false, true);
    return;
  }
  b -= 288;
  // skip_up slice -> bsp[k][perm(n)][128:320], 6x12x12
  cvt_t_body(tile, b % 6, (b / 6) % 12, b / 72, skip_up_W, 384, 4608, bsp_h, nullptr,
             384L * 320, 320, 128, 192, 384, false, true);
}

// ---------------------------------------------------------------------------
// MFMA fp16 GEMM: dbuf LDS, raw barriers + fine vmcnt, XOR bank swizzle.
// EPI=0: f32 store (ATOMIC: atomicAdd, blockIdx.z = K-split).
// EPI=1: fused val/gate SiLU epilogue -> YH fp16 (spec GEMM; B cols permuted).
// EPI=2: f32 store for col<3072; cols [3072,3264) -> asp lat fp16 x12 k (q GEMM).
// ---------------------------------------------------------------------------
template <int NTERMS, int ATOMIC, int EPI>
__global__ __launch_bounds__(256)
void mfma_gemm_kernel(const _Float16* __restrict__ Ah, const _Float16* __restrict__ Al,
                      const _Float16* __restrict__ Bh, const _Float16* __restrict__ Bl,
                      float* __restrict__ C,
                      int Kd, int Nact,
                      long strideA, long strideB, long strideC,
                      const float* __restrict__ HS, _Float16* __restrict__ YH) {
  constexpr int NT2 = (NTERMS > 1) ? 2 : 1;
  __shared__ __align__(16) _Float16 sA[2][NT2][128 * 32];
  __shared__ __align__(16) _Float16 sB[2][NT2][128 * 32];
  int kz, kbeg, kend;
  if (ATOMIC) {
    kz = 0;
    int len = Kd / gridDim.z;
    kbeg = blockIdx.z * len;
    kend = kbeg + len;
  } else {
    kz = blockIdx.z;
    kbeg = 0;
    kend = Kd;
  }
  const _Float16* A0 = Ah + (size_t)kz * strideA;
  const _Float16* B0 = Bh + (size_t)kz * strideB;
  const _Float16* A1 = (NTERMS > 1) ? (Al + (size_t)kz * strideA) : nullptr;
  const _Float16* B1 = (NTERMS > 1) ? (Bl + (size_t)kz * strideB) : nullptr;
  float* Cb = C + (size_t)kz * strideC;
  const int bm0 = blockIdx.y * 128;
  const int bn0 = blockIdx.x * 128;
  const int tid = threadIdx.x;
  const int wave = tid >> 6, lane = tid & 63;
  const int m16 = lane & 15, quad = lane >> 4;
  const int wr = (wave & 1) * 64, wc = (wave >> 1) * 64;

  f32x4 acc[4][4];
#pragma unroll
  for (int i = 0; i < 4; ++i)
#pragma unroll
    for (int j = 0; j < 4; ++j) acc[i][j] = (f32x4){0.f, 0.f, 0.f, 0.f};

  const int lin = tid * 8;                 // LDS slot (halfs), 16 B per thread
  const int lrow = lin >> 5;               // 0..63
  const int lblk = (lin >> 3) & 3;         // 16-B block within row
  const int csw = ((lblk ^ (lrow & 3)) << 3);  // XOR-swizzled source col (halfs)

  auto stage = [&](int k0, int kb) {
    const _Float16* gA = A0 + (size_t)(bm0 + lrow) * Kd + (k0 + csw);
    async16(gA, &sA[kb][0][lin]);
    async16(gA + (size_t)64 * Kd, &sA[kb][0][lin + 2048]);
    const _Float16* gB = B0 + (size_t)(bn0 + lrow) * Kd + (k0 + csw);
    async16(gB, &sB[kb][0][lin]);
    async16(gB + (size_t)64 * Kd, &sB[kb][0][lin + 2048]);
    if constexpr (NTERMS > 1) {
      const _Float16* gA1 = A1 + (size_t)(bm0 + lrow) * Kd + (k0 + csw);
      async16(gA1, &sA[kb][1][lin]);
      async16(gA1 + (size_t)64 * Kd, &sA[kb][1][lin + 2048]);
      const _Float16* gB1 = B1 + (size_t)(bn0 + lrow) * Kd + (k0 + csw);
      async16(gB1, &sB[kb][1][lin]);
      async16(gB1 + (size_t)64 * Kd, &sB[kb][1][lin + 2048]);
    }
  };

  const int niter = (kend - kbeg) / 32;
  stage(kbeg, 0);
  if (niter > 1) stage(kbeg + 32, 1);

  for (int it = 0; it < niter; ++it) {
    if (it == niter - 1)
      __builtin_amdgcn_s_waitcnt(0x0F70);                       // vmcnt(0)
    else
      __builtin_amdgcn_s_waitcnt(NTERMS > 1 ? 0x0F78 : 0x0F74); // vmcnt(8)/vmcnt(4)
    __builtin_amdgcn_s_barrier();
    asm volatile("" ::: "memory");
    const int kb = it & 1;
    half8 a0[4], b0[4];
#pragma unroll
    for (int i = 0; i < 4; ++i) {
      const int rA = wr + i * 16 + m16;
      a0[i] = *(const half8*)&sA[kb][0][rA * 32 + ((quad ^ (rA & 3)) << 3)];
    }
#pragma unroll
    for (int j = 0; j < 4; ++j) {
      const int rB = wc + j * 16 + m16;
      b0[j] = *(const half8*)&sB[kb][0][rB * 32 + ((quad ^ (rB & 3)) << 3)];
    }
    if constexpr (NTERMS == 1) {
#pragma unroll
      for (int i = 0; i < 4; ++i)
#pragma unroll
        for (int j = 0; j < 4; ++j)
          acc[i][j] = __builtin_amdgcn_mfma_f32_16x16x32_f16(a0[i], b0[j], acc[i][j], 0, 0, 0);
    } else {
      half8 a1[4], b1[4];
#pragma unroll
      for (int i = 0; i < 4; ++i) {
        const int rA = wr + i * 16 + m16;
        a1[i] = *(const half8*)&sA[kb][1][rA * 32 + ((quad ^ (rA & 3)) << 3)];
      }
#pragma unroll
      for (int j = 0; j < 4; ++j) {
        const int rB = wc + j * 16 + m16;
        b1[j] = *(const half8*)&sB[kb][1][rB * 32 + ((quad ^ (rB & 3)) << 3)];
      }
#pragma unroll
      for (int i = 0; i < 4; ++i)
#pragma unroll
        for (int j = 0; j < 4; ++j) {
          acc[i][j] = __builtin_amdgcn_mfma_f32_16x16x32_f16(a0[i], b0[j], acc[i][j], 0, 0, 0);
          acc[i][j] = __builtin_amdgcn_mfma_f32_16x16x32_f16(a0[i], b1[j], acc[i][j], 0, 0, 0);
          acc[i][j] = __builtin_amdgcn_mfma_f32_16x16x32_f16(a1[i], b0[j], acc[i][j], 0, 0, 0);
        }
    }
    asm volatile("" ::: "memory");
    __builtin_amdgcn_s_barrier();
    asm volatile("" ::: "memory");
    if (it + 2 < niter) stage(kbeg + (it + 2) * 32, kb);
  }

  // epilogues (C/D layout: col=lane&15, row=quad*4+reg)
  if constexpr (EPI == 1) {
    // fused SiLU: even j-tiles = val, odd = gate (same lane, paired regs)
#pragma unroll
    for (int i = 0; i < 4; ++i) {
      const int row0 = bm0 + wr + i * 16 + quad * 4;
#pragma unroll
      for (int j = 0; j < 4; j += 2) {
        const int colv = bn0 + wc + j * 16 + m16;        // colv%32 == m16
        const int jout = (colv >> 5) * 16 + m16;         // output col in [0,192)
#pragma unroll
        for (int r = 0; r < 4; ++r) {
          float val = acc[i][j][r];
          float g = acc[i][j + 1][r];
          float s = g / (1.f + __expf(-g));
          YH[(size_t)(row0 + r) * 2304 + kz * 192 + jout] = (_Float16)(val * s);
        }
      }
    }
  } else if constexpr (EPI == 2) {
    float hsreg[12];
#pragma unroll
    for (int k = 0; k < 12; ++k) hsreg[k] = HS[k];
#pragma unroll
    for (int i = 0; i < 4; ++i) {
      const int row0 = bm0 + wr + i * 16 + quad * 4;
#pragma unroll
      for (int j = 0; j < 4; ++j) {
        const int col = bn0 + wc + j * 16 + m16;
        if (col < 3072) {
#pragma unroll
          for (int r = 0; r < 4; ++r)
            Cb[(size_t)(row0 + r) * Nact + col] = acc[i][j][r];
        } else if (col < QLN_) {
          const int jj = col - 3072;
#pragma unroll
          for (int r = 0; r < 4; ++r) {
            float v = acc[i][j][r];
            size_t t = (size_t)(row0 + r);
#pragma unroll
            for (int k = 0; k < 12; ++k)
              YH[((size_t)k * NTOK_ + t) * 320 + 128 + jj] = (_Float16)(v * hsreg[k]);
          }
        }
      }
    }
  } else {
#pragma unroll
    for (int i = 0; i < 4; ++i) {
      const int row0 = bm0 + wr + i * 16 + quad * 4;
#pragma unroll
      for (int j = 0; j < 4; ++j) {
        const int col = bn0 + wc + j * 16 + m16;
        if (col < Nact) {
#pragma unroll
          for (int r = 0; r < 4; ++r) {
            if (ATOMIC)
              atomicAdd(&Cb[(size_t)(row0 + r) * Nact + col], acc[i][j][r]);
            else
              Cb[(size_t)(row0 + r) * Nact + col] = acc[i][j][r];
          }
        }
      }
    }
  }
}

// ---------------------------------------------------------------------------
// Depthwise causal conv (CK=4) along l, per channel
// ---------------------------------------------------------------------------
__global__ void conv_kernel(const float* __restrict__ z,
                            const float* __restrict__ ck,
                            float* __restrict__ zc) {
  size_t idx = (size_t)blockIdx.x * 256 + threadIdx.x;
  if (idx >= (size_t)NTOK_ * ZC_) return;
  int c = (int)(idx % ZC_);
  int t = (int)(idx / ZC_);
  int l = t % L_;
  float acc = 0.f;
#pragma unroll
  for (int w = 0; w < 4; ++w) {
    int lw = l - 3 + w;
    if (lw >= 0) acc += z[idx - (size_t)(3 - w) * ZC_] * ck[w * ZC_ + c];
  }
  zc[idx] = acc;
}

// ---------------------------------------------------------------------------
// Scan pass A
// ---------------------------------------------------------------------------
__global__ void pass_a_kernel(const float* __restrict__ zc,
                              const float* __restrict__ theta_tab,
                              const float* __restrict__ score_scale,
                              const float* __restrict__ tanh_scale,
                              const float* __restrict__ slopes_sp,
                              float* __restrict__ csums) {
  const int c = blockIdx.x, k = blockIdx.y, b = blockIdx.z;
  const int tid = threadIdx.x;
  const int m = tid & 3, h = tid >> 2;
  const float theta_v = theta_tab[(k * H_ + h) * M_ + m];
  const float ts = tanh_scale[k], ss = score_scale[k], slope = slopes_sp[k];
  float sre = 0.f, sim = 0.f, dacc = 0.f;
  for (int ll = 0; ll < LC_; ++ll) {
    int l = c * LC_ + ll;
    size_t t = (size_t)b * L_ + l;
    float kv = zc[t * ZC_ + k * H_ + h];
    float sraw = zc[t * ZC_ + 768 + k];
    float lp = fminf(fmaxf(ss * sraw, -20.f), 20.f);
    float pw = __expf(lp - slope * (float)(L_ - 1 - l));
    float ph = fast_tanh(ts * kv) * theta_v;
    float kvp = kv * pw;
    sre += kvp * __cosf(ph);
    sim += kvp * __sinf(ph);
    dacc += pw;
  }
  size_t base = (((size_t)b * K_ + k) * NC_ + c) * 513;
  if (tid == 0) csums[base] = dacc;
  csums[base + 1 + h * 4 + m] = sre;
  csums[base + 1 + 256 + h * 4 + m] = sim;
}

// ---------------------------------------------------------------------------
// Scan pass B
// ---------------------------------------------------------------------------
__global__ void pass_b_kernel(const float* __restrict__ csums,
                              float* __restrict__ cpre) {
  int bk = blockIdx.y;
  int comp = blockIdx.x * 64 + threadIdx.x;
  if (comp >= 513) return;
  float run = 0.f;
  size_t base = (size_t)bk * NC_ * 513 + comp;
  for (int c = 0; c < NC_; ++c) {
    cpre[base + (size_t)c * 513] = run;
    run += csums[base + (size_t)c * 513];
  }
}

// ---------------------------------------------------------------------------
// Scan pass C: replay, contract with q, apply ns*gate, write asp[k][t][0:128]
// ---------------------------------------------------------------------------
__global__ void pass_c_kernel(const float* __restrict__ zc,
                              const float* __restrict__ qlat,
                              const float* __restrict__ theta_tab,
                              const float* __restrict__ w_tab,
                              const float* __restrict__ score_scale,
                              const float* __restrict__ tanh_scale,
                              const float* __restrict__ slopes_sp,
                              const float* __restrict__ cpre,
                              const float* __restrict__ gatelin,
                              const float* __restrict__ gate_b,
                              const float* __restrict__ ns,
                              _Float16* __restrict__ asp) {
  const int c = blockIdx.x, k = blockIdx.y, b = blockIdx.z;
  const int tid = threadIdx.x;
  const int m = tid & 3, h = tid >> 2;
  size_t base = (((size_t)b * K_ + k) * NC_ + c) * 513;
  float den = cpre[base];
  float sre = cpre[base + 1 + h * 4 + m];
  float sim = cpre[base + 1 + 256 + h * 4 + m];
  const float theta_v = theta_tab[(k * H_ + h) * M_ + m];
  const float w = w_tab[(k * H_ + h) * M_ + m];
  const float ts = tanh_scale[k], ss = score_scale[k], slope = slopes_sp[k];
  const float nsv = ns[k * H_ + h];
  const float gb = gate_b[k];
  const int kq = k >> 1;   // NREP = 2
  for (int ll = 0; ll < LC_; ++ll) {
    int l = c * LC_ + ll;
    size_t t = (size_t)b * L_ + l;
    float kv = zc[t * ZC_ + k * H_ + h];
    float sraw = zc[t * ZC_ + 768 + k];
    float lp = fminf(fmaxf(ss * sraw, -20.f), 20.f);
    float pw = __expf(lp - slope * (float)(L_ - 1 - l));
    float ph = fast_tanh(ts * kv) * theta_v;
    float kvp = kv * pw;
    sre += kvp * __cosf(ph);
    sim += kvp * __sinf(ph);
    den += pw;
    float inv = 1.f / fmaxf(den, 1e-4f);
    float s_re = sre * inv, s_im = sim * inv;
    size_t qb = t * QLN_ + (size_t)(((kq * H_ + h) * M_ + m) * 2);
    float qr = qlat[qb], qi = qlat[qb + 1];
    float tr = (s_re * qr + s_im * qi) * w;
    float ti = (s_im * qr - s_re * qi) * w;
    tr += __shfl_xor(tr, 1); tr += __shfl_xor(tr, 2);
    ti += __shfl_xor(ti, 1); ti += __shfl_xor(ti, 2);
    if (m == 0) {
      float g = 1.f / (1.f + __expf(-(gatelin[t * K_ + k] + gb))) * nsv;
      size_t ab = ((size_t)k * NTOK_ + t) * 320;
      asp[ab + h] = (_Float16)(tr * g);
      asp[ab + 64 + h] = (_Float16)(ti * g);
    }
  }
}

// ---------------------------------------------------------------------------
extern "C" void kernel_launch(void* const* d_in, const int* in_sizes, int n_in,
                              void* d_out, int out_size, void* d_ws, size_t ws_size,
                              hipStream_t stream) {
  const float* x            = (const float*)d_in[0];
  const float* W_mem        = (const float*)d_in[1];
  const float* conv_k       = (const float*)d_in[2];
  const float* W_q          = (const float*)d_in[3];
  const float* theta_d_raw  = (const float*)d_in[4];
  const float* decay_slopes = (const float*)d_in[5];
  const float* score_scale  = (const float*)d_in[6];
  const float* tanh_scale   = (const float*)d_in[7];
  const float* W_re         = (const float*)d_in[8];
  const float* W_im         = (const float*)d_in[9];
  const float* norm_scale   = (const float*)d_in[10];
  const float* gate_W       = (const float*)d_in[11];
  const float* gate_b       = (const float*)d_in[12];
  const float* skip_down_W  = (const float*)d_in[13];
  const float* skip_up_W    = (const float*)d_in[14];
  const float* highway_scale= (const float*)d_in[15];
  const float* out_W        = (const float*)d_in[16];
  float* out = (float*)d_out;
  float* ws = (float*)d_ws;

  // ---- f32 region ----
  float* theta_tab = ws;                                  // 3072
  float* w_tab     = theta_tab + 3072;                    // 3072
  float* slopes_sp = w_tab + 3072;                        // 16
  float* z_pre     = slopes_sp + 16;                      // 3,194,880
  float* zc        = z_pre + (size_t)NTOK_ * ZC_;         // 3,194,880
  float* qlat      = zc + (size_t)NTOK_ * ZC_;            // 13,369,344
  float* gatelin   = qlat + (size_t)NTOK_ * QLN_;         // 49,152
  float* csums     = gatelin + (size_t)NTOK_ * K_;        // 787,968
  float* cpre      = csums + (size_t)B_ * K_ * NC_ * 513; // 787,968
  _Float16* y_h    = (_Float16*)(cpre + (size_t)B_ * K_ * NC_ * 513);  // 4096x2304 halfs
  float* f32_end   = (float*)(y_h + (size_t)NTOK_ * 2304);

  // ---- fp16 region ----
  _Float16* fp = (_Float16*)f32_end;
  _Float16* x_h    = fp;                fp += (size_t)NTOK_ * D_;
  _Float16* x_l    = fp;                fp += (size_t)NTOK_ * D_;
  _Float16* wmem_h = fp;                fp += (size_t)896 * 768;
  _Float16* wmem_l = fp;                fp += (size_t)896 * 768;
  _Float16* qlb_h  = fp;                fp += (size_t)QLP_ * 768;   // [W_q^T | skd^T | 0pad]
  _Float16* outw_h = fp;                fp += (size_t)768 * 2304;
  _Float16* asp_h  = fp;                fp += (size_t)K_ * NTOK_ * 320;
  _Float16* bsp_h  = fp;                fp += (size_t)K_ * 384 * 320;

  // zero split-K atomic targets (out 3.1M, z_pre 3.2M floats)
  zero2_kernel<<<(int)((3194880 + 255) / 256), 256, 0, stream>>>(out, (size_t)NTOK_ * D_,
                                                                 z_pre, (size_t)NTOK_ * ZC_);
  precomp_kernel<<<3, 256, 0, stream>>>(theta_d_raw, decay_slopes, theta_tab, w_tab, slopes_sp);

  // conversions
  cvt_split_kernel<<<(NTOK_ * D_ + 255) / 256, 256, 0, stream>>>(x, x_h, x_l, NTOK_ * D_);
  cvtw_kernel<<<6336, 256, 0, stream>>>(W_mem, W_q, skip_down_W, out_W, W_re, W_im, skip_up_W,
                                        wmem_h, wmem_l, qlb_h, outw_h, bsp_h);

  // z_pre += x @ W_mem  (split fp16, split-K=2, atomic)
  mfma_gemm_kernel<3, 1, 0><<<dim3(7, 32, 2), 256, 0, stream>>>(x_h, x_l, wmem_h, wmem_l, z_pre,
                                                                768, ZC_, 0, 0, 0, nullptr, nullptr);
  conv_kernel<<<(int)(((size_t)NTOK_ * ZC_ + 255) / 256), 256, 0, stream>>>(z_pre, conv_k, zc);
  // qlat = x @ [W_q | skip_down]; cols>=3072 -> asp lat fp16 (x12 k, scaled hs)
  mfma_gemm_kernel<1, 0, 2><<<dim3(26, 32, 1), 256, 0, stream>>>(x_h, x_h, qlb_h, qlb_h, qlat,
                                                                 768, QLN_, 0, 0, 0,
                                                                 highway_scale, asp_h);
  // gatelin = x @ gate_W
  gate_kernel<<<NTOK_ / 4, 256, 0, stream>>>(x, gate_W, gatelin);

  // chunked scan (f32)
  pass_a_kernel<<<dim3(NC_, K_, B_), 256, 0, stream>>>(zc, theta_tab, score_scale, tanh_scale, slopes_sp, csums);
  pass_b_kernel<<<dim3(9, B_ * K_), 64, 0, stream>>>(csums, cpre);
  pass_c_kernel<<<dim3(NC_, K_, B_), 256, 0, stream>>>(zc, qlat, theta_tab, w_tab, score_scale, tanh_scale,
                                                       slopes_sp, cpre, gatelin, gate_b, norm_scale, asp_h);

  // batched spec GEMM with fused SiLU -> y_h fp16 directly
  mfma_gemm_kernel<1, 0, 1><<<dim3(3, 32, K_), 256, 0, stream>>>(asp_h, asp_h, bsp_h, bsp_h,
                                                                 (float*)nullptr, 320, 384,
                                                                 (long)NTOK_ * 320, 384L * 320, 0,
                                                                 nullptr, y_h);
  // out += y @ out_W  (split-K=4, atomic)
  mfma_gemm_kernel<1, 1, 0><<<dim3(6, 32, 4), 256, 0, stream>>>(y_h, y_h, outw_h, outw_h, out,
                                                                2304, 768, 0, 0, 0, nullptr, nullptr);
}

// Round 8
// 391.661 us; speedup vs baseline: 1.2228x; 1.0673x over previous
//
#include <hip/hip_runtime.h>
#include <math.h>

#define B_    2
#define L_    2048
#define D_    768
#define K_    12
#define KQ_   6
#define M_    4
#define H_    64
#define ZC_   780      // MEM + K
#define NTOK_ 4096     // B*L
#define NC_   64       // scan chunks per batch
#define LC_   32       // chunk length (L/NC)
#define QLN_  3264     // q (3072) + lat (192) fused N
#define QST_  3072     // qlat f32 row stride (lat cols stored separately)

typedef __attribute__((ext_vector_type(8))) _Float16 half8;
typedef __attribute__((ext_vector_type(4))) float f32x4;

__device__ __forceinline__ float softplus_f(float x) {
  return (x > 20.f) ? x : log1pf(expf(x));
}

__device__ __forceinline__ float fast_tanh(float x) {
  float xx = fminf(fmaxf(x, -10.f), 10.f);
  float e = __expf(2.f * xx);
  return (e - 1.f) / (e + 1.f);
}

// async global->LDS 16B per lane (dest = wave-uniform base + lane*16)
__device__ __forceinline__ void async16(const _Float16* g, _Float16* l) {
  __builtin_amdgcn_global_load_lds(
      (const __attribute__((address_space(1))) unsigned int*)g,
      (__attribute__((address_space(3))) unsigned int*)l, 16, 0, 0);
}

// val/gate 16-interleave permutation for spec-B columns
__device__ __forceinline__ int permcol(int n) {
  int isg = (n >= 192) ? 1 : 0;
  int j = n - 192 * isg;
  return (j >> 4) * 32 + (isg << 4) + (j & 15);
}

// ---------------------------------------------------------------------------
__global__ void zero2_kernel(float* __restrict__ a, size_t na,
                             float* __restrict__ b, size_t nb) {
  size_t i = (size_t)blockIdx.x * 256 + threadIdx.x;
  if (i < na) a[i] = 0.f;
  if (i < nb) b[i] = 0.f;
}

// ---------------------------------------------------------------------------
__global__ void precomp_kernel(const float* __restrict__ theta_d_raw,
                               const float* __restrict__ decay,
                               float* __restrict__ theta_tab,
                               float* __restrict__ w_tab,
                               float* __restrict__ slopes_sp) {
  int idx = blockIdx.x * 256 + threadIdx.x;
  if (idx < K_) slopes_sp[idx] = softplus_f(decay[idx]);
  if (idx >= K_ * H_) return;
  float td[M_], ta[M_];
#pragma unroll
  for (int m = 0; m < M_; ++m) td[m] = softplus_f(theta_d_raw[idx * M_ + m]) + 1e-4f;
  ta[0] = td[0];
#pragma unroll
  for (int m = 1; m < M_; ++m) ta[m] = ta[m - 1] + td[m];
  float total = ta[M_ - 1];
  float rs = 2.999f / total;
#pragma unroll
  for (int m = 0; m < M_; ++m) theta_tab[idx * M_ + m] = 0.001f + ta[m] * rs;
  float d0 = (ta[1] - ta[0]) * rs;
  float d1 = (ta[2] - ta[1]) * rs;
  float d2 = (ta[3] - ta[2]) * rs;
  w_tab[idx * M_ + 0] = 0.5f * d0;
  w_tab[idx * M_ + 1] = 0.5f * (d0 + d1);
  w_tab[idx * M_ + 2] = 0.5f * (d1 + d2);
  w_tab[idx * M_ + 3] = 0.5f * d2;
}

// ---------------------------------------------------------------------------
__global__ __launch_bounds__(256) void gate_kernel(const float* __restrict__ x,
                                                   const float* __restrict__ gW,
                                                   float* __restrict__ gatelin) {
  __shared__ float gws[768 * 12];
  for (int i = threadIdx.x; i < 768 * 12; i += 256) gws[i] = gW[i];
  __syncthreads();
  const int wave = threadIdx.x >> 6, lane = threadIdx.x & 63;
  const int t = blockIdx.x * 4 + wave;
  const float* xt = x + (size_t)t * D_;
  float acc[12];
#pragma unroll
  for (int k = 0; k < 12; ++k) acc[k] = 0.f;
#pragma unroll
  for (int i = 0; i < 12; ++i) {
    float xv = xt[lane + 64 * i];
    const float* w = &gws[(lane + 64 * i) * 12];
#pragma unroll
    for (int k = 0; k < 12; ++k) acc[k] += xv * w[k];
  }
#pragma unroll
  for (int k = 0; k < 12; ++k) {
    acc[k] += __shfl_xor(acc[k], 32);
    acc[k] += __shfl_xor(acc[k], 16);
    acc[k] += __shfl_xor(acc[k], 8);
    acc[k] += __shfl_xor(acc[k], 4);
    acc[k] += __shfl_xor(acc[k], 2);
    acc[k] += __shfl_xor(acc[k], 1);
  }
  if (lane < 12) {
    float v = 0.f;
#pragma unroll
    for (int k = 0; k < 12; ++k)
      if (lane == k) v = acc[k];
    gatelin[(size_t)t * K_ + lane] = v;
  }
}

// ---------------------------------------------------------------------------
__global__ void cvt_split_kernel(const float* __restrict__ src,
                                 _Float16* __restrict__ h,
                                 _Float16* __restrict__ l, int n) {
  int gid = blockIdx.x * 256 + threadIdx.x;
  if (gid >= n) return;
  float v = src[gid];
  _Float16 hi = (_Float16)v;
  h[gid] = hi;
  l[gid] = (_Float16)(v - (float)hi);
}

// ---------------------------------------------------------------------------
// Transpose+convert body; optional perm + scale
// ---------------------------------------------------------------------------
__device__ __forceinline__ void cvt_t_body(float (*tile)[33], int bx, int by, int kz,
                                           const float* src, long sKs, int srs,
                                           _Float16* dh, _Float16* dl,
                                           long dKs, int dst, int doff,
                                           int R, int Nact, bool wlo, bool perm,
                                           float scale) {
  const float* s = src + (size_t)kz * sKs;
  _Float16* dhh = dh + (size_t)kz * dKs;
  _Float16* dll = dl ? (dl + (size_t)kz * dKs) : nullptr;
  const int kb = bx * 32;
  const int nb = by * 32;
  const int tx = threadIdx.x & 31, ty = threadIdx.x >> 5;
  for (int i = ty; i < 32; i += 8) {
    int kk = kb + i, n = nb + tx;
    tile[i][tx] = (kk < R && n < Nact) ? s[(size_t)kk * srs + n] : 0.f;
  }
  __syncthreads();
  for (int i = ty; i < 32; i += 8) {
    int n = nb + i, kk = kb + tx;
    if (kk < R) {
      float v = tile[tx][i] * scale;
      _Float16 hi = (_Float16)v;
      int dn = perm ? permcol(n) : n;
      size_t di = (size_t)dn * dst + doff + kk;
      dhh[di] = hi;
      if (wlo) dll[di] = (_Float16)(v - (float)hi);
    }
  }
}

// ---------------------------------------------------------------------------
// Merged weight conversion. highway_scale folded into bsp rows [128:320].
// ---------------------------------------------------------------------------
__global__ void cvtw_kernel(const float* __restrict__ W_mem, const float* __restrict__ W_q,
                            const float* __restrict__ skip_down_W, const float* __restrict__ out_W,
                            const float* __restrict__ W_re, const float* __restrict__ W_im,
                            const float* __restrict__ skip_up_W, const float* __restrict__ hs,
                            _Float16* __restrict__ wmem_h, _Float16* __restrict__ wmem_l,
                            _Float16* __restrict__ qlb_h, _Float16* __restrict__ outw_h,
                            _Float16* __restrict__ bsp_h) {
  __shared__ float tile[32][33];
  int b = blockIdx.x;
  if (b < 672) {           // W_mem -> wmem (hi+lo), 24x28
    cvt_t_body(tile, b % 24, b / 24, 0, W_mem, 0, ZC_, wmem_h, wmem_l, 0, 768, 0, 768, ZC_, true, false, 1.f);
    return;
  }
  b -= 672;
  if (b < 2304) {          // W_q -> qlb rows [0,3072), 24x96
    cvt_t_body(tile, b % 24, b / 24, 0, W_q, 0, 3072, qlb_h, nullptr, 0, 768, 0, 768, 3072, false, false, 1.f);
    return;
  }
  b -= 2304;
  if (b < 192) {           // skip_down -> qlb rows [3072,3328), 24x8
    cvt_t_body(tile, b % 24, b / 24, 0, skip_down_W, 0, 192, qlb_h + (size_t)3072 * 768, nullptr,
               0, 768, 0, 768, 192, false, false, 1.f);
    return;
  }
  b -= 192;
  if (b < 1728) {          // out_W -> outw, 72x24
    cvt_t_body(tile, b % 72, b / 72, 0, out_W, 0, 768, outw_h, nullptr, 0, 2304, 0, 2304, 768, false, false, 1.f);
    return;
  }
  b -= 1728;
  if (b < 288) {           // W_re -> bsp[k][perm(n)][0:64], 2x12x12
    cvt_t_body(tile, b % 2, (b / 2) % 12, b / 24, W_re, 64L * 384, 384, bsp_h, nullptr,
               384L * 320, 320, 0, 64, 384, false, true, 1.f);
    return;
  }
  b -= 288;
  if (b < 288) {           // W_im -> bsp[k][perm(n)][64:128]
    cvt_t_body(tile, b % 2, (b / 2) % 12, b / 24, W_im, 64L * 384, 384, bsp_h, nullptr,
               384L * 320, 320, 64, 64, 384, false, true, 1.f);
    return;
  }
  b -= 288;
  // skip_up slice -> bsp[k][perm(n)][128:320] scaled by hs[k], 6x12x12
  int kz = b / 72;
  cvt_t_body(tile, b % 6, (b / 6) % 12, kz, skip_up_W, 384, 4608, bsp_h, nullptr,
             384L * 320, 320, 128, 192, 384, false, true, hs[kz]);
}

// ---------------------------------------------------------------------------
// MFMA fp16 GEMM: dbuf LDS, raw barriers + fine vmcnt, XOR(row>>1) swizzle.
// EPI=0: f32 store (ATOMIC: atomicAdd, blockIdx.z = K-split).
// EPI=1: spec GEMM: A staged from split source (Ah per-k 128-stride for
//        k<128, A2 shared 192-stride for k>=128); fused val/gate SiLU -> YH.
// EPI=2: q GEMM: f32 store (stride 3072) for col<3072; cols [3072,3264) ->
//        lat_h fp16 once (YH).
// ---------------------------------------------------------------------------
template <int NTERMS, int ATOMIC, int EPI>
__global__ __launch_bounds__(256)
void mfma_gemm_kernel(const _Float16* __restrict__ Ah, const _Float16* __restrict__ Al,
                      const _Float16* __restrict__ Bh, const _Float16* __restrict__ Bl,
                      float* __restrict__ C,
                      int Kd, int Nact,
                      long strideA, long strideB, long strideC,
                      const _Float16* __restrict__ A2, _Float16* __restrict__ YH) {
  constexpr int NT2 = (NTERMS > 1) ? 2 : 1;
  __shared__ __align__(16) _Float16 sA[2][NT2][128 * 32];
  __shared__ __align__(16) _Float16 sB[2][NT2][128 * 32];
  int kz, kbeg, kend;
  if (ATOMIC) {
    kz = 0;
    int len = Kd / gridDim.z;
    kbeg = blockIdx.z * len;
    kend = kbeg + len;
  } else {
    kz = blockIdx.z;
    kbeg = 0;
    kend = Kd;
  }
  const _Float16* A0 = Ah + (size_t)kz * strideA;
  const _Float16* B0 = Bh + (size_t)kz * strideB;
  const _Float16* A1 = (NTERMS > 1) ? (Al + (size_t)kz * strideA) : nullptr;
  const _Float16* B1 = (NTERMS > 1) ? (Bl + (size_t)kz * strideB) : nullptr;
  float* Cb = C + (size_t)kz * strideC;
  const int bm0 = blockIdx.y * 128;
  const int bn0 = blockIdx.x * 128;
  const int tid = threadIdx.x;
  const int wave = tid >> 6, lane = tid & 63;
  const int m16 = lane & 15, quad = lane >> 4;
  const int wr = (wave & 1) * 64, wc = (wave >> 1) * 64;

  f32x4 acc[4][4];
#pragma unroll
  for (int i = 0; i < 4; ++i)
#pragma unroll
    for (int j = 0; j < 4; ++j) acc[i][j] = (f32x4){0.f, 0.f, 0.f, 0.f};

  const int lin = tid * 8;                 // LDS slot (halfs), 16 B per thread
  const int lrow = lin >> 5;               // 0..63
  const int lblk = (lin >> 3) & 3;         // 16-B block within row
  // XOR swizzle with (row>>1)&3: 8 distinct 4-bank positions per 8 lanes
  const int csw = ((lblk ^ ((lrow >> 1) & 3)) << 3);

  auto stage = [&](int k0, int kb) {
    if constexpr (EPI == 1) {
      if (k0 < 128) {
        const _Float16* gA = A0 + (size_t)(bm0 + lrow) * 128 + (k0 + csw);
        async16(gA, &sA[kb][0][lin]);
        async16(gA + (size_t)64 * 128, &sA[kb][0][lin + 2048]);
      } else {
        const _Float16* gA = A2 + (size_t)(bm0 + lrow) * 192 + (k0 - 128 + csw);
        async16(gA, &sA[kb][0][lin]);
        async16(gA + (size_t)64 * 192, &sA[kb][0][lin + 2048]);
      }
    } else {
      const _Float16* gA = A0 + (size_t)(bm0 + lrow) * Kd + (k0 + csw);
      async16(gA, &sA[kb][0][lin]);
      async16(gA + (size_t)64 * Kd, &sA[kb][0][lin + 2048]);
    }
    const _Float16* gB = B0 + (size_t)(bn0 + lrow) * Kd + (k0 + csw);
    async16(gB, &sB[kb][0][lin]);
    async16(gB + (size_t)64 * Kd, &sB[kb][0][lin + 2048]);
    if constexpr (NTERMS > 1) {
      const _Float16* gA1 = A1 + (size_t)(bm0 + lrow) * Kd + (k0 + csw);
      async16(gA1, &sA[kb][1][lin]);
      async16(gA1 + (size_t)64 * Kd, &sA[kb][1][lin + 2048]);
      const _Float16* gB1 = B1 + (size_t)(bn0 + lrow) * Kd + (k0 + csw);
      async16(gB1, &sB[kb][1][lin]);
      async16(gB1 + (size_t)64 * Kd, &sB[kb][1][lin + 2048]);
    }
  };

  const int niter = (kend - kbeg) / 32;
  stage(kbeg, 0);
  if (niter > 1) stage(kbeg + 32, 1);

  for (int it = 0; it < niter; ++it) {
    if (it == niter - 1)
      __builtin_amdgcn_s_waitcnt(0x0F70);                       // vmcnt(0)
    else
      __builtin_amdgcn_s_waitcnt(NTERMS > 1 ? 0x0F78 : 0x0F74); // vmcnt(8)/vmcnt(4)
    __builtin_amdgcn_s_barrier();
    asm volatile("" ::: "memory");
    const int kb = it & 1;
    half8 a0[4], b0[4];
#pragma unroll
    for (int i = 0; i < 4; ++i) {
      const int rA = wr + i * 16 + m16;
      a0[i] = *(const half8*)&sA[kb][0][rA * 32 + ((quad ^ ((rA >> 1) & 3)) << 3)];
    }
#pragma unroll
    for (int j = 0; j < 4; ++j) {
      const int rB = wc + j * 16 + m16;
      b0[j] = *(const half8*)&sB[kb][0][rB * 32 + ((quad ^ ((rB >> 1) & 3)) << 3)];
    }
    if constexpr (NTERMS == 1) {
#pragma unroll
      for (int i = 0; i < 4; ++i)
#pragma unroll
        for (int j = 0; j < 4; ++j)
          acc[i][j] = __builtin_amdgcn_mfma_f32_16x16x32_f16(a0[i], b0[j], acc[i][j], 0, 0, 0);
    } else {
      half8 a1[4], b1[4];
#pragma unroll
      for (int i = 0; i < 4; ++i) {
        const int rA = wr + i * 16 + m16;
        a1[i] = *(const half8*)&sA[kb][1][rA * 32 + ((quad ^ ((rA >> 1) & 3)) << 3)];
      }
#pragma unroll
      for (int j = 0; j < 4; ++j) {
        const int rB = wc + j * 16 + m16;
        b1[j] = *(const half8*)&sB[kb][1][rB * 32 + ((quad ^ ((rB >> 1) & 3)) << 3)];
      }
#pragma unroll
      for (int i = 0; i < 4; ++i)
#pragma unroll
        for (int j = 0; j < 4; ++j) {
          acc[i][j] = __builtin_amdgcn_mfma_f32_16x16x32_f16(a0[i], b0[j], acc[i][j], 0, 0, 0);
          acc[i][j] = __builtin_amdgcn_mfma_f32_16x16x32_f16(a0[i], b1[j], acc[i][j], 0, 0, 0);
          acc[i][j] = __builtin_amdgcn_mfma_f32_16x16x32_f16(a1[i], b0[j], acc[i][j], 0, 0, 0);
        }
    }
    asm volatile("" ::: "memory");
    __builtin_amdgcn_s_barrier();
    asm volatile("" ::: "memory");
    if (it + 2 < niter) stage(kbeg + (it + 2) * 32, kb);
  }

  // epilogues (C/D layout: col=lane&15, row=quad*4+reg)
  if constexpr (EPI == 1) {
#pragma unroll
    for (int i = 0; i < 4; ++i) {
      const int row0 = bm0 + wr + i * 16 + quad * 4;
#pragma unroll
      for (int j = 0; j < 4; j += 2) {
        const int colv = bn0 + wc + j * 16 + m16;
        const int jout = (colv >> 5) * 16 + m16;
#pragma unroll
        for (int r = 0; r < 4; ++r) {
          float val = acc[i][j][r];
          float g = acc[i][j + 1][r];
          float s = g / (1.f + __expf(-g));
          YH[(size_t)(row0 + r) * 2304 + kz * 192 + jout] = (_Float16)(val * s);
        }
      }
    }
  } else if constexpr (EPI == 2) {
#pragma unroll
    for (int i = 0; i < 4; ++i) {
      const int row0 = bm0 + wr + i * 16 + quad * 4;
#pragma unroll
      for (int j = 0; j < 4; ++j) {
        const int col = bn0 + wc + j * 16 + m16;
        if (col < 3072) {
#pragma unroll
          for (int r = 0; r < 4; ++r)
            Cb[(size_t)(row0 + r) * QST_ + col] = acc[i][j][r];
        } else if (col < QLN_) {
          const int jj = col - 3072;
#pragma unroll
          for (int r = 0; r < 4; ++r)
            YH[(size_t)(row0 + r) * 192 + jj] = (_Float16)acc[i][j][r];
        }
      }
    }
  } else {
#pragma unroll
    for (int i = 0; i < 4; ++i) {
      const int row0 = bm0 + wr + i * 16 + quad * 4;
#pragma unroll
      for (int j = 0; j < 4; ++j) {
        const int col = bn0 + wc + j * 16 + m16;
        if (col < Nact) {
#pragma unroll
          for (int r = 0; r < 4; ++r) {
            if (ATOMIC)
              atomicAdd(&Cb[(size_t)(row0 + r) * Nact + col], acc[i][j][r]);
            else
              Cb[(size_t)(row0 + r) * Nact + col] = acc[i][j][r];
          }
        }
      }
    }
  }
}

// ---------------------------------------------------------------------------
__global__ void conv_kernel(const float* __restrict__ z,
                            const float* __restrict__ ck,
                            float* __restrict__ zc) {
  size_t idx = (size_t)blockIdx.x * 256 + threadIdx.x;
  if (idx >= (size_t)NTOK_ * ZC_) return;
  int c = (int)(idx % ZC_);
  int t = (int)(idx / ZC_);
  int l = t % L_;
  float acc = 0.f;
#pragma unroll
  for (int w = 0; w < 4; ++w) {
    int lw = l - 3 + w;
    if (lw >= 0) acc += z[idx - (size_t)(3 - w) * ZC_] * ck[w * ZC_ + c];
  }
  zc[idx] = acc;
}

// ---------------------------------------------------------------------------
__global__ void pass_a_kernel(const float* __restrict__ zc,
                              const float* __restrict__ theta_tab,
                              const float* __restrict__ score_scale,
                              const float* __restrict__ tanh_scale,
                              const float* __restrict__ slopes_sp,
                              float* __restrict__ csums) {
  const int c = blockIdx.x, k = blockIdx.y, b = blockIdx.z;
  const int tid = threadIdx.x;
  const int m = tid & 3, h = tid >> 2;
  const float theta_v = theta_tab[(k * H_ + h) * M_ + m];
  const float ts = tanh_scale[k], ss = score_scale[k], slope = slopes_sp[k];
  float sre = 0.f, sim = 0.f, dacc = 0.f;
  for (int ll = 0; ll < LC_; ++ll) {
    int l = c * LC_ + ll;
    size_t t = (size_t)b * L_ + l;
    float kv = zc[t * ZC_ + k * H_ + h];
    float sraw = zc[t * ZC_ + 768 + k];
    float lp = fminf(fmaxf(ss * sraw, -20.f), 20.f);
    float pw = __expf(lp - slope * (float)(L_ - 1 - l));
    float ph = fast_tanh(ts * kv) * theta_v;
    float kvp = kv * pw;
    sre += kvp * __cosf(ph);
    sim += kvp * __sinf(ph);
    dacc += pw;
  }
  size_t base = (((size_t)b * K_ + k) * NC_ + c) * 513;
  if (tid == 0) csums[base] = dacc;
  csums[base + 1 + h * 4 + m] = sre;
  csums[base + 1 + 256 + h * 4 + m] = sim;
}

// ---------------------------------------------------------------------------
__global__ void pass_b_kernel(const float* __restrict__ csums,
                              float* __restrict__ cpre) {
  int bk = blockIdx.y;
  int comp = blockIdx.x * 64 + threadIdx.x;
  if (comp >= 513) return;
  float run = 0.f;
  size_t base = (size_t)bk * NC_ * 513 + comp;
  for (int c = 0; c < NC_; ++c) {
    cpre[base + (size_t)c * 513] = run;
    run += csums[base + (size_t)c * 513];
  }
}

// ---------------------------------------------------------------------------
// Scan pass C: writes fp16 into asp2[k][t][0:128] (128-stride)
// ---------------------------------------------------------------------------
__global__ void pass_c_kernel(const float* __restrict__ zc,
                              const float* __restrict__ qlat,
                              const float* __restrict__ theta_tab,
                              const float* __restrict__ w_tab,
                              const float* __restrict__ score_scale,
                              const float* __restrict__ tanh_scale,
                              const float* __restrict__ slopes_sp,
                              const float* __restrict__ cpre,
                              const float* __restrict__ gatelin,
                              const float* __restrict__ gate_b,
                              const float* __restrict__ ns,
                              _Float16* __restrict__ asp) {
  const int c = blockIdx.x, k = blockIdx.y, b = blockIdx.z;
  const int tid = threadIdx.x;
  const int m = tid & 3, h = tid >> 2;
  size_t base = (((size_t)b * K_ + k) * NC_ + c) * 513;
  float den = cpre[base];
  float sre = cpre[base + 1 + h * 4 + m];
  float sim = cpre[base + 1 + 256 + h * 4 + m];
  const float theta_v = theta_tab[(k * H_ + h) * M_ + m];
  const float w = w_tab[(k * H_ + h) * M_ + m];
  const float ts = tanh_scale[k], ss = score_scale[k], slope = slopes_sp[k];
  const float nsv = ns[k * H_ + h];
  const float gb = gate_b[k];
  const int kq = k >> 1;   // NREP = 2
  for (int ll = 0; ll < LC_; ++ll) {
    int l = c * LC_ + ll;
    size_t t = (size_t)b * L_ + l;
    float kv = zc[t * ZC_ + k * H_ + h];
    float sraw = zc[t * ZC_ + 768 + k];
    float lp = fminf(fmaxf(ss * sraw, -20.f), 20.f);
    float pw = __expf(lp - slope * (float)(L_ - 1 - l));
    float ph = fast_tanh(ts * kv) * theta_v;
    float kvp = kv * pw;
    sre += kvp * __cosf(ph);
    sim += kvp * __sinf(ph);
    den += pw;
    float inv = 1.f / fmaxf(den, 1e-4f);
    float s_re = sre * inv, s_im = sim * inv;
    size_t qb = t * QST_ + (size_t)(((kq * H_ + h) * M_ + m) * 2);
    float qr = qlat[qb], qi = qlat[qb + 1];
    float tr = (s_re * qr + s_im * qi) * w;
    float ti = (s_im * qr - s_re * qi) * w;
    tr += __shfl_xor(tr, 1); tr += __shfl_xor(tr, 2);
    ti += __shfl_xor(ti, 1); ti += __shfl_xor(ti, 2);
    if (m == 0) {
      float g = 1.f / (1.f + __expf(-(gatelin[t * K_ + k] + gb))) * nsv;
      size_t ab = ((size_t)k * NTOK_ + t) * 128;
      asp[ab + h] = (_Float16)(tr * g);
      asp[ab + 64 + h] = (_Float16)(ti * g);
    }
  }
}

// ---------------------------------------------------------------------------
extern "C" void kernel_launch(void* const* d_in, const int* in_sizes, int n_in,
                              void* d_out, int out_size, void* d_ws, size_t ws_size,
                              hipStream_t stream) {
  const float* x            = (const float*)d_in[0];
  const float* W_mem        = (const float*)d_in[1];
  const float* conv_k       = (const float*)d_in[2];
  const float* W_q          = (const float*)d_in[3];
  const float* theta_d_raw  = (const float*)d_in[4];
  const float* decay_slopes = (const float*)d_in[5];
  const float* score_scale  = (const float*)d_in[6];
  const float* tanh_scale   = (const float*)d_in[7];
  const float* W_re         = (const float*)d_in[8];
  const float* W_im         = (const float*)d_in[9];
  const float* norm_scale   = (const float*)d_in[10];
  const float* gate_W       = (const float*)d_in[11];
  const float* gate_b       = (const float*)d_in[12];
  const float* skip_down_W  = (const float*)d_in[13];
  const float* skip_up_W    = (const float*)d_in[14];
  const float* highway_scale= (const float*)d_in[15];
  const float* out_W        = (const float*)d_in[16];
  float* out = (float*)d_out;
  float* ws = (float*)d_ws;

  // ---- f32 region ----
  float* theta_tab = ws;                                  // 3072
  float* w_tab     = theta_tab + 3072;                    // 3072
  float* slopes_sp = w_tab + 3072;                        // 16
  float* z_pre     = slopes_sp + 16;                      // 3,194,880
  float* zc        = z_pre + (size_t)NTOK_ * ZC_;         // 3,194,880
  float* qlat      = zc + (size_t)NTOK_ * ZC_;            // 4096*3072 = 12,582,912
  float* gatelin   = qlat + (size_t)NTOK_ * QST_;         // 49,152
  float* csums     = gatelin + (size_t)NTOK_ * K_;        // 787,968
  float* cpre      = csums + (size_t)B_ * K_ * NC_ * 513; // 787,968
  _Float16* y_h    = (_Float16*)(cpre + (size_t)B_ * K_ * NC_ * 513);  // 4096x2304 halfs
  float* f32_end   = (float*)(y_h + (size_t)NTOK_ * 2304);

  // ---- fp16 region ----
  _Float16* fp = (_Float16*)f32_end;
  _Float16* x_h    = fp;                fp += (size_t)NTOK_ * D_;
  _Float16* x_l    = fp;                fp += (size_t)NTOK_ * D_;
  _Float16* wmem_h = fp;                fp += (size_t)896 * 768;
  _Float16* wmem_l = fp;                fp += (size_t)896 * 768;
  _Float16* qlb_h  = fp;                fp += (size_t)3328 * 768;   // [W_q^T | skd^T | 0pad]
  _Float16* outw_h = fp;                fp += (size_t)768 * 2304;
  _Float16* asp2_h = fp;                fp += (size_t)K_ * NTOK_ * 128;
  _Float16* bsp_h  = fp;                fp += (size_t)K_ * 384 * 320;
  _Float16* lat_h  = fp;                fp += (size_t)NTOK_ * 192;

  // zero split-K atomic targets (out 3.1M, z_pre 3.2M floats)
  zero2_kernel<<<(int)((3194880 + 255) / 256), 256, 0, stream>>>(out, (size_t)NTOK_ * D_,
                                                                 z_pre, (size_t)NTOK_ * ZC_);
  precomp_kernel<<<3, 256, 0, stream>>>(theta_d_raw, decay_slopes, theta_tab, w_tab, slopes_sp);

  // conversions
  cvt_split_kernel<<<(NTOK_ * D_ + 255) / 256, 256, 0, stream>>>(x, x_h, x_l, NTOK_ * D_);
  cvtw_kernel<<<6336, 256, 0, stream>>>(W_mem, W_q, skip_down_W, out_W, W_re, W_im, skip_up_W,
                                        highway_scale, wmem_h, wmem_l, qlb_h, outw_h, bsp_h);

  // z_pre += x @ W_mem  (split fp16, split-K=2, atomic)
  mfma_gemm_kernel<3, 1, 0><<<dim3(7, 32, 2), 256, 0, stream>>>(x_h, x_l, wmem_h, wmem_l, z_pre,
                                                                768, ZC_, 0, 0, 0, nullptr, nullptr);
  conv_kernel<<<(int)(((size_t)NTOK_ * ZC_ + 255) / 256), 256, 0, stream>>>(z_pre, conv_k, zc);
  // qlat = x @ [W_q | skip_down]; q cols f32 (stride 3072); lat cols -> lat_h fp16
  mfma_gemm_kernel<1, 0, 2><<<dim3(26, 32, 1), 256, 0, stream>>>(x_h, x_h, qlb_h, qlb_h, qlat,
                                                                 768, QLN_, 0, 0, 0,
                                                                 nullptr, lat_h);
  // gatelin = x @ gate_W
  gate_kernel<<<NTOK_ / 4, 256, 0, stream>>>(x, gate_W, gatelin);

  // chunked scan (f32)
  pass_a_kernel<<<dim3(NC_, K_, B_), 256, 0, stream>>>(zc, theta_tab, score_scale, tanh_scale, slopes_sp, csums);
  pass_b_kernel<<<dim3(9, B_ * K_), 64, 0, stream>>>(csums, cpre);
  pass_c_kernel<<<dim3(NC_, K_, B_), 256, 0, stream>>>(zc, qlat, theta_tab, w_tab, score_scale, tanh_scale,
                                                       slopes_sp, cpre, gatelin, gate_b, norm_scale, asp2_h);

  // batched spec GEMM (A = [asp2 per-k | lat_h shared], hs folded into bsp)
  // with fused SiLU -> y_h fp16
  mfma_gemm_kernel<1, 0, 1><<<dim3(3, 32, K_), 256, 0, stream>>>(asp2_h, nullptr, bsp_h, nullptr,
                                                                 (float*)nullptr, 320, 384,
                                                                 (long)NTOK_ * 128, 384L * 320, 0,
                                                                 lat_h, y_h);
  // out += y @ out_W  (split-K=4, atomic)
  mfma_gemm_kernel<1, 1, 0><<<dim3(6, 32, 4), 256, 0, stream>>>(y_h, y_h, outw_h, outw_h, out,
                                                                2304, 768, 0, 0, 0, nullptr, nullptr);
}

// Round 9
// 389.444 us; speedup vs baseline: 1.2297x; 1.0057x over previous
//
#include <hip/hip_runtime.h>
#include <math.h>

#define B_    2
#define L_    2048
#define D_    768
#define K_    12
#define KQ_   6
#define M_    4
#define H_    64
#define ZC_   780      // MEM + K
#define NTOK_ 4096     // B*L
#define NC_   64       // scan chunks per batch
#define LC_   32       // chunk length (L/NC)
#define QLN_  3264     // q (3072) + lat (192) fused N
#define QST_  3072     // q fp16 row stride (lat cols stored separately)

typedef __attribute__((ext_vector_type(8))) _Float16 half8;
typedef __attribute__((ext_vector_type(4))) float f32x4;

__device__ __forceinline__ float softplus_f(float x) {
  return (x > 20.f) ? x : log1pf(expf(x));
}

__device__ __forceinline__ float fast_tanh(float x) {
  float xx = fminf(fmaxf(x, -10.f), 10.f);
  float e = __expf(2.f * xx);
  return (e - 1.f) / (e + 1.f);
}

// async global->LDS 16B per lane (dest = wave-uniform base + lane*16)
__device__ __forceinline__ void async16(const _Float16* g, _Float16* l) {
  __builtin_amdgcn_global_load_lds(
      (const __attribute__((address_space(1))) unsigned int*)g,
      (__attribute__((address_space(3))) unsigned int*)l, 16, 0, 0);
}

// val/gate 16-interleave permutation for spec-B columns
__device__ __forceinline__ int permcol(int n) {
  int isg = (n >= 192) ? 1 : 0;
  int j = n - 192 * isg;
  return (j >> 4) * 32 + (isg << 4) + (j & 15);
}

// ---------------------------------------------------------------------------
__global__ void zero2_kernel(float* __restrict__ a, size_t na,
                             float* __restrict__ b, size_t nb) {
  size_t i = (size_t)blockIdx.x * 256 + threadIdx.x;
  if (i < na) a[i] = 0.f;
  if (i < nb) b[i] = 0.f;
}

// ---------------------------------------------------------------------------
__global__ void precomp_kernel(const float* __restrict__ theta_d_raw,
                               const float* __restrict__ decay,
                               float* __restrict__ theta_tab,
                               float* __restrict__ w_tab,
                               float* __restrict__ slopes_sp) {
  int idx = blockIdx.x * 256 + threadIdx.x;
  if (idx < K_) slopes_sp[idx] = softplus_f(decay[idx]);
  if (idx >= K_ * H_) return;
  float td[M_], ta[M_];
#pragma unroll
  for (int m = 0; m < M_; ++m) td[m] = softplus_f(theta_d_raw[idx * M_ + m]) + 1e-4f;
  ta[0] = td[0];
#pragma unroll
  for (int m = 1; m < M_; ++m) ta[m] = ta[m - 1] + td[m];
  float total = ta[M_ - 1];
  float rs = 2.999f / total;
#pragma unroll
  for (int m = 0; m < M_; ++m) theta_tab[idx * M_ + m] = 0.001f + ta[m] * rs;
  float d0 = (ta[1] - ta[0]) * rs;
  float d1 = (ta[2] - ta[1]) * rs;
  float d2 = (ta[3] - ta[2]) * rs;
  w_tab[idx * M_ + 0] = 0.5f * d0;
  w_tab[idx * M_ + 1] = 0.5f * (d0 + d1);
  w_tab[idx * M_ + 2] = 0.5f * (d1 + d2);
  w_tab[idx * M_ + 3] = 0.5f * d2;
}

// ---------------------------------------------------------------------------
__global__ __launch_bounds__(256) void gate_kernel(const float* __restrict__ x,
                                                   const float* __restrict__ gW,
                                                   float* __restrict__ gatelin) {
  __shared__ float gws[768 * 12];
  for (int i = threadIdx.x; i < 768 * 12; i += 256) gws[i] = gW[i];
  __syncthreads();
  const int wave = threadIdx.x >> 6, lane = threadIdx.x & 63;
  const int t = blockIdx.x * 4 + wave;
  const float* xt = x + (size_t)t * D_;
  float acc[12];
#pragma unroll
  for (int k = 0; k < 12; ++k) acc[k] = 0.f;
#pragma unroll
  for (int i = 0; i < 12; ++i) {
    float xv = xt[lane + 64 * i];
    const float* w = &gws[(lane + 64 * i) * 12];
#pragma unroll
    for (int k = 0; k < 12; ++k) acc[k] += xv * w[k];
  }
#pragma unroll
  for (int k = 0; k < 12; ++k) {
    acc[k] += __shfl_xor(acc[k], 32);
    acc[k] += __shfl_xor(acc[k], 16);
    acc[k] += __shfl_xor(acc[k], 8);
    acc[k] += __shfl_xor(acc[k], 4);
    acc[k] += __shfl_xor(acc[k], 2);
    acc[k] += __shfl_xor(acc[k], 1);
  }
  if (lane < 12) {
    float v = 0.f;
#pragma unroll
    for (int k = 0; k < 12; ++k)
      if (lane == k) v = acc[k];
    gatelin[(size_t)t * K_ + lane] = v;
  }
}

// ---------------------------------------------------------------------------
__global__ void cvt_split_kernel(const float* __restrict__ src,
                                 _Float16* __restrict__ h,
                                 _Float16* __restrict__ l, int n) {
  int gid = blockIdx.x * 256 + threadIdx.x;
  if (gid >= n) return;
  float v = src[gid];
  _Float16 hi = (_Float16)v;
  h[gid] = hi;
  l[gid] = (_Float16)(v - (float)hi);
}

// ---------------------------------------------------------------------------
// Transpose+convert body; optional perm + scale
// ---------------------------------------------------------------------------
__device__ __forceinline__ void cvt_t_body(float (*tile)[33], int bx, int by, int kz,
                                           const float* src, long sKs, int srs,
                                           _Float16* dh, _Float16* dl,
                                           long dKs, int dst, int doff,
                                           int R, int Nact, bool wlo, bool perm,
                                           float scale) {
  const float* s = src + (size_t)kz * sKs;
  _Float16* dhh = dh + (size_t)kz * dKs;
  _Float16* dll = dl ? (dl + (size_t)kz * dKs) : nullptr;
  const int kb = bx * 32;
  const int nb = by * 32;
  const int tx = threadIdx.x & 31, ty = threadIdx.x >> 5;
  for (int i = ty; i < 32; i += 8) {
    int kk = kb + i, n = nb + tx;
    tile[i][tx] = (kk < R && n < Nact) ? s[(size_t)kk * srs + n] : 0.f;
  }
  __syncthreads();
  for (int i = ty; i < 32; i += 8) {
    int n = nb + i, kk = kb + tx;
    if (kk < R) {
      float v = tile[tx][i] * scale;
      _Float16 hi = (_Float16)v;
      int dn = perm ? permcol(n) : n;
      size_t di = (size_t)dn * dst + doff + kk;
      dhh[di] = hi;
      if (wlo) dll[di] = (_Float16)(v - (float)hi);
    }
  }
}

// ---------------------------------------------------------------------------
// Merged weight conversion. highway_scale folded into bsp rows [128:320].
// ---------------------------------------------------------------------------
__global__ void cvtw_kernel(const float* __restrict__ W_mem, const float* __restrict__ W_q,
                            const float* __restrict__ skip_down_W, const float* __restrict__ out_W,
                            const float* __restrict__ W_re, const float* __restrict__ W_im,
                            const float* __restrict__ skip_up_W, const float* __restrict__ hs,
                            _Float16* __restrict__ wmem_h, _Float16* __restrict__ wmem_l,
                            _Float16* __restrict__ qlb_h, _Float16* __restrict__ outw_h,
                            _Float16* __restrict__ bsp_h) {
  __shared__ float tile[32][33];
  int b = blockIdx.x;
  if (b < 672) {           // W_mem -> wmem (hi+lo), 24x28
    cvt_t_body(tile, b % 24, b / 24, 0, W_mem, 0, ZC_, wmem_h, wmem_l, 0, 768, 0, 768, ZC_, true, false, 1.f);
    return;
  }
  b -= 672;
  if (b < 2304) {          // W_q -> qlb rows [0,3072), 24x96
    cvt_t_body(tile, b % 24, b / 24, 0, W_q, 0, 3072, qlb_h, nullptr, 0, 768, 0, 768, 3072, false, false, 1.f);
    return;
  }
  b -= 2304;
  if (b < 192) {           // skip_down -> qlb rows [3072,3328), 24x8
    cvt_t_body(tile, b % 24, b / 24, 0, skip_down_W, 0, 192, qlb_h + (size_t)3072 * 768, nullptr,
               0, 768, 0, 768, 192, false, false, 1.f);
    return;
  }
  b -= 192;
  if (b < 1728) {          // out_W -> outw, 72x24
    cvt_t_body(tile, b % 72, b / 72, 0, out_W, 0, 768, outw_h, nullptr, 0, 2304, 0, 2304, 768, false, false, 1.f);
    return;
  }
  b -= 1728;
  if (b < 288) {           // W_re -> bsp[k][perm(n)][0:64], 2x12x12
    cvt_t_body(tile, b % 2, (b / 2) % 12, b / 24, W_re, 64L * 384, 384, bsp_h, nullptr,
               384L * 320, 320, 0, 64, 384, false, true, 1.f);
    return;
  }
  b -= 288;
  if (b < 288) {           // W_im -> bsp[k][perm(n)][64:128]
    cvt_t_body(tile, b % 2, (b / 2) % 12, b / 24, W_im, 64L * 384, 384, bsp_h, nullptr,
               384L * 320, 320, 64, 64, 384, false, true, 1.f);
    return;
  }
  b -= 288;
  // skip_up slice -> bsp[k][perm(n)][128:320] scaled by hs[k], 6x12x12
  int kz = b / 72;
  cvt_t_body(tile, b % 6, (b / 6) % 12, kz, skip_up_W, 384, 4608, bsp_h, nullptr,
             384L * 320, 320, 128, 192, 384, false, true, hs[kz]);
}

// ---------------------------------------------------------------------------
// MFMA fp16 GEMM: dbuf LDS, raw barriers + fine vmcnt, XOR(row>>1) swizzle.
// EPI=0: f32 store (ATOMIC: atomicAdd, blockIdx.z = K-split).
// EPI=1: spec GEMM: A staged from split source (Ah per-k 128-stride for
//        k<128, A2 shared 192-stride for k>=128); fused val/gate SiLU -> YH.
// EPI=2: q GEMM: fp16 store (stride QST_, via (_Float16*)C) for col<3072;
//        cols [3072,3264) -> lat_h fp16 (YH).
// ---------------------------------------------------------------------------
template <int NTERMS, int ATOMIC, int EPI>
__global__ __launch_bounds__(256)
void mfma_gemm_kernel(const _Float16* __restrict__ Ah, const _Float16* __restrict__ Al,
                      const _Float16* __restrict__ Bh, const _Float16* __restrict__ Bl,
                      float* __restrict__ C,
                      int Kd, int Nact,
                      long strideA, long strideB, long strideC,
                      const _Float16* __restrict__ A2, _Float16* __restrict__ YH) {
  constexpr int NT2 = (NTERMS > 1) ? 2 : 1;
  __shared__ __align__(16) _Float16 sA[2][NT2][128 * 32];
  __shared__ __align__(16) _Float16 sB[2][NT2][128 * 32];
  int kz, kbeg, kend;
  if (ATOMIC) {
    kz = 0;
    int len = Kd / gridDim.z;
    kbeg = blockIdx.z * len;
    kend = kbeg + len;
  } else {
    kz = blockIdx.z;
    kbeg = 0;
    kend = Kd;
  }
  const _Float16* A0 = Ah + (size_t)kz * strideA;
  const _Float16* B0 = Bh + (size_t)kz * strideB;
  const _Float16* A1 = (NTERMS > 1) ? (Al + (size_t)kz * strideA) : nullptr;
  const _Float16* B1 = (NTERMS > 1) ? (Bl + (size_t)kz * strideB) : nullptr;
  float* Cb = C + (size_t)kz * strideC;
  const int bm0 = blockIdx.y * 128;
  const int bn0 = blockIdx.x * 128;
  const int tid = threadIdx.x;
  const int wave = tid >> 6, lane = tid & 63;
  const int m16 = lane & 15, quad = lane >> 4;
  const int wr = (wave & 1) * 64, wc = (wave >> 1) * 64;

  f32x4 acc[4][4];
#pragma unroll
  for (int i = 0; i < 4; ++i)
#pragma unroll
    for (int j = 0; j < 4; ++j) acc[i][j] = (f32x4){0.f, 0.f, 0.f, 0.f};

  const int lin = tid * 8;                 // LDS slot (halfs), 16 B per thread
  const int lrow = lin >> 5;               // 0..63
  const int lblk = (lin >> 3) & 3;         // 16-B block within row
  // XOR swizzle with (row>>1)&3: 8 distinct 4-bank positions per 8 lanes
  const int csw = ((lblk ^ ((lrow >> 1) & 3)) << 3);

  auto stage = [&](int k0, int kb) {
    if constexpr (EPI == 1) {
      if (k0 < 128) {
        const _Float16* gA = A0 + (size_t)(bm0 + lrow) * 128 + (k0 + csw);
        async16(gA, &sA[kb][0][lin]);
        async16(gA + (size_t)64 * 128, &sA[kb][0][lin + 2048]);
      } else {
        const _Float16* gA = A2 + (size_t)(bm0 + lrow) * 192 + (k0 - 128 + csw);
        async16(gA, &sA[kb][0][lin]);
        async16(gA + (size_t)64 * 192, &sA[kb][0][lin + 2048]);
      }
    } else {
      const _Float16* gA = A0 + (size_t)(bm0 + lrow) * Kd + (k0 + csw);
      async16(gA, &sA[kb][0][lin]);
      async16(gA + (size_t)64 * Kd, &sA[kb][0][lin + 2048]);
    }
    const _Float16* gB = B0 + (size_t)(bn0 + lrow) * Kd + (k0 + csw);
    async16(gB, &sB[kb][0][lin]);
    async16(gB + (size_t)64 * Kd, &sB[kb][0][lin + 2048]);
    if constexpr (NTERMS > 1) {
      const _Float16* gA1 = A1 + (size_t)(bm0 + lrow) * Kd + (k0 + csw);
      async16(gA1, &sA[kb][1][lin]);
      async16(gA1 + (size_t)64 * Kd, &sA[kb][1][lin + 2048]);
      const _Float16* gB1 = B1 + (size_t)(bn0 + lrow) * Kd + (k0 + csw);
      async16(gB1, &sB[kb][1][lin]);
      async16(gB1 + (size_t)64 * Kd, &sB[kb][1][lin + 2048]);
    }
  };

  const int niter = (kend - kbeg) / 32;
  stage(kbeg, 0);
  if (niter > 1) stage(kbeg + 32, 1);

  for (int it = 0; it < niter; ++it) {
    if (it == niter - 1)
      __builtin_amdgcn_s_waitcnt(0x0F70);                       // vmcnt(0)
    else
      __builtin_amdgcn_s_waitcnt(NTERMS > 1 ? 0x0F78 : 0x0F74); // vmcnt(8)/vmcnt(4)
    __builtin_amdgcn_s_barrier();
    asm volatile("" ::: "memory");
    const int kb = it & 1;
    half8 a0[4], b0[4];
#pragma unroll
    for (int i = 0; i < 4; ++i) {
      const int rA = wr + i * 16 + m16;
      a0[i] = *(const half8*)&sA[kb][0][rA * 32 + ((quad ^ ((rA >> 1) & 3)) << 3)];
    }
#pragma unroll
    for (int j = 0; j < 4; ++j) {
      const int rB = wc + j * 16 + m16;
      b0[j] = *(const half8*)&sB[kb][0][rB * 32 + ((quad ^ ((rB >> 1) & 3)) << 3)];
    }
    if constexpr (NTERMS == 1) {
#pragma unroll
      for (int i = 0; i < 4; ++i)
#pragma unroll
        for (int j = 0; j < 4; ++j)
          acc[i][j] = __builtin_amdgcn_mfma_f32_16x16x32_f16(a0[i], b0[j], acc[i][j], 0, 0, 0);
    } else {
      half8 a1[4], b1[4];
#pragma unroll
      for (int i = 0; i < 4; ++i) {
        const int rA = wr + i * 16 + m16;
        a1[i] = *(const half8*)&sA[kb][1][rA * 32 + ((quad ^ ((rA >> 1) & 3)) << 3)];
      }
#pragma unroll
      for (int j = 0; j < 4; ++j) {
        const int rB = wc + j * 16 + m16;
        b1[j] = *(const half8*)&sB[kb][1][rB * 32 + ((quad ^ ((rB >> 1) & 3)) << 3)];
      }
#pragma unroll
      for (int i = 0; i < 4; ++i)
#pragma unroll
        for (int j = 0; j < 4; ++j) {
          acc[i][j] = __builtin_amdgcn_mfma_f32_16x16x32_f16(a0[i], b0[j], acc[i][j], 0, 0, 0);
          acc[i][j] = __builtin_amdgcn_mfma_f32_16x16x32_f16(a0[i], b1[j], acc[i][j], 0, 0, 0);
          acc[i][j] = __builtin_amdgcn_mfma_f32_16x16x32_f16(a1[i], b0[j], acc[i][j], 0, 0, 0);
        }
    }
    asm volatile("" ::: "memory");
    __builtin_amdgcn_s_barrier();
    asm volatile("" ::: "memory");
    if (it + 2 < niter) stage(kbeg + (it + 2) * 32, kb);
  }

  // epilogues (C/D layout: col=lane&15, row=quad*4+reg)
  if constexpr (EPI == 1) {
#pragma unroll
    for (int i = 0; i < 4; ++i) {
      const int row0 = bm0 + wr + i * 16 + quad * 4;
#pragma unroll
      for (int j = 0; j < 4; j += 2) {
        const int colv = bn0 + wc + j * 16 + m16;
        const int jout = (colv >> 5) * 16 + m16;
#pragma unroll
        for (int r = 0; r < 4; ++r) {
          float val = acc[i][j][r];
          float g = acc[i][j + 1][r];
          float s = g / (1.f + __expf(-g));
          YH[(size_t)(row0 + r) * 2304 + kz * 192 + jout] = (_Float16)(val * s);
        }
      }
    }
  } else if constexpr (EPI == 2) {
    _Float16* qh = (_Float16*)Cb;
#pragma unroll
    for (int i = 0; i < 4; ++i) {
      const int row0 = bm0 + wr + i * 16 + quad * 4;
#pragma unroll
      for (int j = 0; j < 4; ++j) {
        const int col = bn0 + wc + j * 16 + m16;
        if (col < 3072) {
#pragma unroll
          for (int r = 0; r < 4; ++r)
            qh[(size_t)(row0 + r) * QST_ + col] = (_Float16)acc[i][j][r];
        } else if (col < QLN_) {
          const int jj = col - 3072;
#pragma unroll
          for (int r = 0; r < 4; ++r)
            YH[(size_t)(row0 + r) * 192 + jj] = (_Float16)acc[i][j][r];
        }
      }
    }
  } else {
#pragma unroll
    for (int i = 0; i < 4; ++i) {
      const int row0 = bm0 + wr + i * 16 + quad * 4;
#pragma unroll
      for (int j = 0; j < 4; ++j) {
        const int col = bn0 + wc + j * 16 + m16;
        if (col < Nact) {
#pragma unroll
          for (int r = 0; r < 4; ++r) {
            if (ATOMIC)
              atomicAdd(&Cb[(size_t)(row0 + r) * Nact + col], acc[i][j][r]);
            else
              Cb[(size_t)(row0 + r) * Nact + col] = acc[i][j][r];
          }
        }
      }
    }
  }
}

// ---------------------------------------------------------------------------
// Scan pass A with fused causal conv (sliding 4-tap window over z_pre)
// ---------------------------------------------------------------------------
__global__ void pass_a_kernel(const float* __restrict__ zp,
                              const float* __restrict__ ck,
                              const float* __restrict__ theta_tab,
                              const float* __restrict__ score_scale,
                              const float* __restrict__ tanh_scale,
                              const float* __restrict__ slopes_sp,
                              float* __restrict__ csums) {
  const int c = blockIdx.x, k = blockIdx.y, b = blockIdx.z;
  const int tid = threadIdx.x;
  const int m = tid & 3, h = tid >> 2;
  const int chk = k * H_ + h;        // kv channel
  const int chs = 768 + k;           // sraw channel
  const float theta_v = theta_tab[chk * M_ + m];
  const float ts = tanh_scale[k], ss = score_scale[k], slope = slopes_sp[k];
  float ckv[4], cks[4];
#pragma unroll
  for (int w = 0; w < 4; ++w) { ckv[w] = ck[w * ZC_ + chk]; cks[w] = ck[w * ZC_ + chs]; }
  const int l0 = c * LC_;
  // preamble window: z at l0-3, l0-2, l0-1 (0 if l<0)
  float zk3 = 0.f, zk2 = 0.f, zk1 = 0.f, zs3 = 0.f, zs2 = 0.f, zs1 = 0.f;
#pragma unroll
  for (int p = 0; p < 3; ++p) {
    int lp = l0 - 3 + p;
    if (lp >= 0) {
      size_t tp = (size_t)b * L_ + lp;
      float zk = zp[tp * ZC_ + chk], zs = zp[tp * ZC_ + chs];
      if (p == 0) { zk3 = zk; zs3 = zs; }
      else if (p == 1) { zk2 = zk; zs2 = zs; }
      else { zk1 = zk; zs1 = zs; }
    }
  }
  float sre = 0.f, sim = 0.f, dacc = 0.f;
  for (int ll = 0; ll < LC_; ++ll) {
    int l = l0 + ll;
    size_t t = (size_t)b * L_ + l;
    float zk0 = zp[t * ZC_ + chk];
    float zs0 = zp[t * ZC_ + chs];
    float kv = zk3 * ckv[0] + zk2 * ckv[1] + zk1 * ckv[2] + zk0 * ckv[3];
    float sraw = zs3 * cks[0] + zs2 * cks[1] + zs1 * cks[2] + zs0 * cks[3];
    zk3 = zk2; zk2 = zk1; zk1 = zk0;
    zs3 = zs2; zs2 = zs1; zs1 = zs0;
    float lp = fminf(fmaxf(ss * sraw, -20.f), 20.f);
    float pw = __expf(lp - slope * (float)(L_ - 1 - l));
    float ph = fast_tanh(ts * kv) * theta_v;
    float kvp = kv * pw;
    sre += kvp * __cosf(ph);
    sim += kvp * __sinf(ph);
    dacc += pw;
  }
  size_t base = (((size_t)b * K_ + k) * NC_ + c) * 513;
  if (tid == 0) csums[base] = dacc;
  csums[base + 1 + h * 4 + m] = sre;
  csums[base + 1 + 256 + h * 4 + m] = sim;
}

// ---------------------------------------------------------------------------
__global__ void pass_b_kernel(const float* __restrict__ csums,
                              float* __restrict__ cpre) {
  int bk = blockIdx.y;
  int comp = blockIdx.x * 64 + threadIdx.x;
  if (comp >= 513) return;
  float run = 0.f;
  size_t base = (size_t)bk * NC_ * 513 + comp;
  for (int c = 0; c < NC_; ++c) {
    cpre[base + (size_t)c * 513] = run;
    run += csums[base + (size_t)c * 513];
  }
}

// ---------------------------------------------------------------------------
// Scan pass C: fused conv replay, contract with fp16 q, apply ns*gate,
// write fp16 into asp2[k][t][0:128] (128-stride)
// ---------------------------------------------------------------------------
__global__ void pass_c_kernel(const float* __restrict__ zp,
                              const float* __restrict__ ck,
                              const _Float16* __restrict__ qh,
                              const float* __restrict__ theta_tab,
                              const float* __restrict__ w_tab,
                              const float* __restrict__ score_scale,
                              const float* __restrict__ tanh_scale,
                              const float* __restrict__ slopes_sp,
                              const float* __restrict__ cpre,
                              const float* __restrict__ gatelin,
                              const float* __restrict__ gate_b,
                              const float* __restrict__ ns,
                              _Float16* __restrict__ asp) {
  const int c = blockIdx.x, k = blockIdx.y, b = blockIdx.z;
  const int tid = threadIdx.x;
  const int m = tid & 3, h = tid >> 2;
  const int chk = k * H_ + h;
  const int chs = 768 + k;
  size_t base = (((size_t)b * K_ + k) * NC_ + c) * 513;
  float den = cpre[base];
  float sre = cpre[base + 1 + h * 4 + m];
  float sim = cpre[base + 1 + 256 + h * 4 + m];
  const float theta_v = theta_tab[chk * M_ + m];
  const float w = w_tab[chk * M_ + m];
  const float ts = tanh_scale[k], ss = score_scale[k], slope = slopes_sp[k];
  const float nsv = ns[chk];
  const float gb = gate_b[k];
  const int kq = k >> 1;   // NREP = 2
  float ckv[4], cks[4];
#pragma unroll
  for (int ww = 0; ww < 4; ++ww) { ckv[ww] = ck[ww * ZC_ + chk]; cks[ww] = ck[ww * ZC_ + chs]; }
  const int l0 = c * LC_;
  float zk3 = 0.f, zk2 = 0.f, zk1 = 0.f, zs3 = 0.f, zs2 = 0.f, zs1 = 0.f;
#pragma unroll
  for (int p = 0; p < 3; ++p) {
    int lp = l0 - 3 + p;
    if (lp >= 0) {
      size_t tp = (size_t)b * L_ + lp;
      float zk = zp[tp * ZC_ + chk], zs = zp[tp * ZC_ + chs];
      if (p == 0) { zk3 = zk; zs3 = zs; }
      else if (p == 1) { zk2 = zk; zs2 = zs; }
      else { zk1 = zk; zs1 = zs; }
    }
  }
  const int qidx = ((kq * H_ + h) * M_ + m) * 2;
  for (int ll = 0; ll < LC_; ++ll) {
    int l = l0 + ll;
    size_t t = (size_t)b * L_ + l;
    float zk0 = zp[t * ZC_ + chk];
    float zs0 = zp[t * ZC_ + chs];
    float kv = zk3 * ckv[0] + zk2 * ckv[1] + zk1 * ckv[2] + zk0 * ckv[3];
    float sraw = zs3 * cks[0] + zs2 * cks[1] + zs1 * cks[2] + zs0 * cks[3];
    zk3 = zk2; zk2 = zk1; zk1 = zk0;
    zs3 = zs2; zs2 = zs1; zs1 = zs0;
    float lp = fminf(fmaxf(ss * sraw, -20.f), 20.f);
    float pw = __expf(lp - slope * (float)(L_ - 1 - l));
    float ph = fast_tanh(ts * kv) * theta_v;
    float kvp = kv * pw;
    sre += kvp * __cosf(ph);
    sim += kvp * __sinf(ph);
    den += pw;
    float inv = 1.f / fmaxf(den, 1e-4f);
    float s_re = sre * inv, s_im = sim * inv;
    size_t qb = t * QST_ + qidx;
    float qr = (float)qh[qb], qi = (float)qh[qb + 1];
    float tr = (s_re * qr + s_im * qi) * w;
    float ti = (s_im * qr - s_re * qi) * w;
    tr += __shfl_xor(tr, 1); tr += __shfl_xor(tr, 2);
    ti += __shfl_xor(ti, 1); ti += __shfl_xor(ti, 2);
    if (m == 0) {
      float g = 1.f / (1.f + __expf(-(gatelin[t * K_ + k] + gb))) * nsv;
      size_t ab = ((size_t)k * NTOK_ + t) * 128;
      asp[ab + h] = (_Float16)(tr * g);
      asp[ab + 64 + h] = (_Float16)(ti * g);
    }
  }
}

// ---------------------------------------------------------------------------
extern "C" void kernel_launch(void* const* d_in, const int* in_sizes, int n_in,
                              void* d_out, int out_size, void* d_ws, size_t ws_size,
                              hipStream_t stream) {
  const float* x            = (const float*)d_in[0];
  const float* W_mem        = (const float*)d_in[1];
  const float* conv_k       = (const float*)d_in[2];
  const float* W_q          = (const float*)d_in[3];
  const float* theta_d_raw  = (const float*)d_in[4];
  const float* decay_slopes = (const float*)d_in[5];
  const float* score_scale  = (const float*)d_in[6];
  const float* tanh_scale   = (const float*)d_in[7];
  const float* W_re         = (const float*)d_in[8];
  const float* W_im         = (const float*)d_in[9];
  const float* norm_scale   = (const float*)d_in[10];
  const float* gate_W       = (const float*)d_in[11];
  const float* gate_b       = (const float*)d_in[12];
  const float* skip_down_W  = (const float*)d_in[13];
  const float* skip_up_W    = (const float*)d_in[14];
  const float* highway_scale= (const float*)d_in[15];
  const float* out_W        = (const float*)d_in[16];
  float* out = (float*)d_out;
  float* ws = (float*)d_ws;

  // ---- f32 region ----
  float* theta_tab = ws;                                  // 3072
  float* w_tab     = theta_tab + 3072;                    // 3072
  float* slopes_sp = w_tab + 3072;                        // 16
  float* z_pre     = slopes_sp + 16;                      // 3,194,880
  float* gatelin   = z_pre + (size_t)NTOK_ * ZC_;         // 49,152
  float* csums     = gatelin + (size_t)NTOK_ * K_;        // 787,968
  float* cpre      = csums + (size_t)B_ * K_ * NC_ * 513; // 787,968
  _Float16* q_h    = (_Float16*)(cpre + (size_t)B_ * K_ * NC_ * 513); // 4096x3072 halfs
  _Float16* y_h    = q_h + (size_t)NTOK_ * QST_;          // 4096x2304 halfs
  float* f32_end   = (float*)(y_h + (size_t)NTOK_ * 2304);

  // ---- fp16 region ----
  _Float16* fp = (_Float16*)f32_end;
  _Float16* x_h    = fp;                fp += (size_t)NTOK_ * D_;
  _Float16* x_l    = fp;                fp += (size_t)NTOK_ * D_;
  _Float16* wmem_h = fp;                fp += (size_t)896 * 768;
  _Float16* wmem_l = fp;                fp += (size_t)896 * 768;
  _Float16* qlb_h  = fp;                fp += (size_t)3328 * 768;   // [W_q^T | skd^T | 0pad]
  _Float16* outw_h = fp;                fp += (size_t)768 * 2304;
  _Float16* asp2_h = fp;                fp += (size_t)K_ * NTOK_ * 128;
  _Float16* bsp_h  = fp;                fp += (size_t)K_ * 384 * 320;
  _Float16* lat_h  = fp;                fp += (size_t)NTOK_ * 192;

  // zero split-K atomic targets (out 3.1M, z_pre 3.2M floats)
  zero2_kernel<<<(int)((3194880 + 255) / 256), 256, 0, stream>>>(out, (size_t)NTOK_ * D_,
                                                                 z_pre, (size_t)NTOK_ * ZC_);
  precomp_kernel<<<3, 256, 0, stream>>>(theta_d_raw, decay_slopes, theta_tab, w_tab, slopes_sp);

  // conversions
  cvt_split_kernel<<<(NTOK_ * D_ + 255) / 256, 256, 0, stream>>>(x, x_h, x_l, NTOK_ * D_);
  cvtw_kernel<<<6336, 256, 0, stream>>>(W_mem, W_q, skip_down_W, out_W, W_re, W_im, skip_up_W,
                                        highway_scale, wmem_h, wmem_l, qlb_h, outw_h, bsp_h);

  // z_pre += x @ W_mem  (split fp16, split-K=2, atomic); conv fused into scans
  mfma_gemm_kernel<3, 1, 0><<<dim3(7, 32, 2), 256, 0, stream>>>(x_h, x_l, wmem_h, wmem_l, z_pre,
                                                                768, ZC_, 0, 0, 0, nullptr, nullptr);
  // q_h = fp16(x @ [W_q | skip_down]); lat cols -> lat_h fp16
  mfma_gemm_kernel<1, 0, 2><<<dim3(26, 32, 1), 256, 0, stream>>>(x_h, x_h, qlb_h, qlb_h, (float*)q_h,
                                                                 768, QLN_, 0, 0, 0,
                                                                 nullptr, lat_h);
  // gatelin = x @ gate_W
  gate_kernel<<<NTOK_ / 4, 256, 0, stream>>>(x, gate_W, gatelin);

  // chunked scan (f32) with fused causal conv
  pass_a_kernel<<<dim3(NC_, K_, B_), 256, 0, stream>>>(z_pre, conv_k, theta_tab, score_scale,
                                                       tanh_scale, slopes_sp, csums);
  pass_b_kernel<<<dim3(9, B_ * K_), 64, 0, stream>>>(csums, cpre);
  pass_c_kernel<<<dim3(NC_, K_, B_), 256, 0, stream>>>(z_pre, conv_k, q_h, theta_tab, w_tab,
                                                       score_scale, tanh_scale, slopes_sp, cpre,
                                                       gatelin, gate_b, norm_scale, asp2_h);

  // batched spec GEMM (A = [asp2 per-k | lat_h shared], hs folded into bsp)
  // with fused SiLU -> y_h fp16
  mfma_gemm_kernel<1, 0, 1><<<dim3(3, 32, K_), 256, 0, stream>>>(asp2_h, nullptr, bsp_h, nullptr,
                                                                 (float*)nullptr, 320, 384,
                                                                 (long)NTOK_ * 128, 384L * 320, 0,
                                                                 lat_h, y_h);
  // out += y @ out_W  (split-K=4, atomic)
  mfma_gemm_kernel<1, 1, 0><<<dim3(6, 32, 4), 256, 0, stream>>>(y_h, y_h, outw_h, outw_h, out,
                                                                2304, 768, 0, 0, 0, nullptr, nullptr);
}

// Round 10
// 336.351 us; speedup vs baseline: 1.4239x; 1.1579x over previous
//
#include <hip/hip_runtime.h>
#include <math.h>

#define B_    2
#define L_    2048
#define D_    768
#define K_    12
#define KQ_   6
#define M_    4
#define H_    64
#define ZC_   780      // MEM + K
#define NTOK_ 4096     // B*L
#define NC_   64       // scan chunks per batch
#define LC_   32       // chunk length (L/NC)
#define QST_  3072     // q fp16 row stride
#define XPN_  4224     // merged projection N: 3328 (q+skd+pad) + 896 (wmem)

typedef __attribute__((ext_vector_type(8))) _Float16 half8;
typedef __attribute__((ext_vector_type(4))) float f32x4;

__device__ __forceinline__ float softplus_f(float x) {
  return (x > 20.f) ? x : log1pf(expf(x));
}

__device__ __forceinline__ float fast_tanh(float x) {
  float xx = fminf(fmaxf(x, -10.f), 10.f);
  float e = __expf(2.f * xx);
  return (e - 1.f) / (e + 1.f);
}

// async global->LDS 16B per lane (dest = wave-uniform base + lane*16)
__device__ __forceinline__ void async16(const _Float16* g, _Float16* l) {
  __builtin_amdgcn_global_load_lds(
      (const __attribute__((address_space(1))) unsigned int*)g,
      (__attribute__((address_space(3))) unsigned int*)l, 16, 0, 0);
}

// val/gate 16-interleave permutation for spec-B columns
__device__ __forceinline__ int permcol(int n) {
  int isg = (n >= 192) ? 1 : 0;
  int j = n - 192 * isg;
  return (j >> 4) * 32 + (isg << 4) + (j & 15);
}

// ---------------------------------------------------------------------------
__global__ void zero1_kernel(float* __restrict__ a, size_t na) {
  size_t i = (size_t)blockIdx.x * 256 + threadIdx.x;
  if (i < na) a[i] = 0.f;
}

// ---------------------------------------------------------------------------
__global__ void precomp_kernel(const float* __restrict__ theta_d_raw,
                               const float* __restrict__ decay,
                               float* __restrict__ theta_tab,
                               float* __restrict__ w_tab,
                               float* __restrict__ slopes_sp) {
  int idx = blockIdx.x * 256 + threadIdx.x;
  if (idx < K_) slopes_sp[idx] = softplus_f(decay[idx]);
  if (idx >= K_ * H_) return;
  float td[M_], ta[M_];
#pragma unroll
  for (int m = 0; m < M_; ++m) td[m] = softplus_f(theta_d_raw[idx * M_ + m]) + 1e-4f;
  ta[0] = td[0];
#pragma unroll
  for (int m = 1; m < M_; ++m) ta[m] = ta[m - 1] + td[m];
  float total = ta[M_ - 1];
  float rs = 2.999f / total;
#pragma unroll
  for (int m = 0; m < M_; ++m) theta_tab[idx * M_ + m] = 0.001f + ta[m] * rs;
  float d0 = (ta[1] - ta[0]) * rs;
  float d1 = (ta[2] - ta[1]) * rs;
  float d2 = (ta[3] - ta[2]) * rs;
  w_tab[idx * M_ + 0] = 0.5f * d0;
  w_tab[idx * M_ + 1] = 0.5f * (d0 + d1);
  w_tab[idx * M_ + 2] = 0.5f * (d1 + d2);
  w_tab[idx * M_ + 3] = 0.5f * d2;
}

// ---------------------------------------------------------------------------
__global__ __launch_bounds__(256) void gate_kernel(const float* __restrict__ x,
                                                   const float* __restrict__ gW,
                                                   float* __restrict__ gatelin) {
  __shared__ float gws[768 * 12];
  for (int i = threadIdx.x; i < 768 * 12; i += 256) gws[i] = gW[i];
  __syncthreads();
  const int wave = threadIdx.x >> 6, lane = threadIdx.x & 63;
  const int t = blockIdx.x * 4 + wave;
  const float* xt = x + (size_t)t * D_;
  float acc[12];
#pragma unroll
  for (int k = 0; k < 12; ++k) acc[k] = 0.f;
#pragma unroll
  for (int i = 0; i < 12; ++i) {
    float xv = xt[lane + 64 * i];
    const float* w = &gws[(lane + 64 * i) * 12];
#pragma unroll
    for (int k = 0; k < 12; ++k) acc[k] += xv * w[k];
  }
#pragma unroll
  for (int k = 0; k < 12; ++k) {
    acc[k] += __shfl_xor(acc[k], 32);
    acc[k] += __shfl_xor(acc[k], 16);
    acc[k] += __shfl_xor(acc[k], 8);
    acc[k] += __shfl_xor(acc[k], 4);
    acc[k] += __shfl_xor(acc[k], 2);
    acc[k] += __shfl_xor(acc[k], 1);
  }
  if (lane < 12) {
    float v = 0.f;
#pragma unroll
    for (int k = 0; k < 12; ++k)
      if (lane == k) v = acc[k];
    gatelin[(size_t)t * K_ + lane] = v;
  }
}

// ---------------------------------------------------------------------------
__global__ void cvt_h_kernel(const float* __restrict__ src,
                             _Float16* __restrict__ h, int n) {
  int gid = blockIdx.x * 256 + threadIdx.x;
  if (gid >= n) return;
  h[gid] = (_Float16)src[gid];
}

// ---------------------------------------------------------------------------
// Transpose+convert body; optional perm + scale
// ---------------------------------------------------------------------------
__device__ __forceinline__ void cvt_t_body(float (*tile)[33], int bx, int by, int kz,
                                           const float* src, long sKs, int srs,
                                           _Float16* dh, long dKs, int dst, int doff,
                                           int R, int Nact, bool perm, float scale) {
  const float* s = src + (size_t)kz * sKs;
  _Float16* dhh = dh + (size_t)kz * dKs;
  const int kb = bx * 32;
  const int nb = by * 32;
  const int tx = threadIdx.x & 31, ty = threadIdx.x >> 5;
  for (int i = ty; i < 32; i += 8) {
    int kk = kb + i, n = nb + tx;
    tile[i][tx] = (kk < R && n < Nact) ? s[(size_t)kk * srs + n] : 0.f;
  }
  __syncthreads();
  for (int i = ty; i < 32; i += 8) {
    int n = nb + i, kk = kb + tx;
    if (kk < R) {
      float v = tile[tx][i] * scale;
      int dn = perm ? permcol(n) : n;
      dhh[(size_t)dn * dst + doff + kk] = (_Float16)v;
    }
  }
}

// ---------------------------------------------------------------------------
// Merged weight conversion (one dispatch).
// xpb layout (rows x 768): [W_q^T 0:3072 | skd^T 3072:3264 | pad | W_mem^T 3328:4108]
// ---------------------------------------------------------------------------
__global__ void cvtw_kernel(const float* __restrict__ W_mem, const float* __restrict__ W_q,
                            const float* __restrict__ skip_down_W, const float* __restrict__ out_W,
                            const float* __restrict__ W_re, const float* __restrict__ W_im,
                            const float* __restrict__ skip_up_W, const float* __restrict__ hs,
                            _Float16* __restrict__ xpb_h, _Float16* __restrict__ outw_h,
                            _Float16* __restrict__ bsp_h) {
  __shared__ float tile[32][33];
  int b = blockIdx.x;
  if (b < 672) {           // W_mem -> xpb rows [3328,4108), 24x28
    cvt_t_body(tile, b % 24, b / 24, 0, W_mem, 0, ZC_, xpb_h + (size_t)3328 * 768,
               0, 768, 0, 768, ZC_, false, 1.f);
    return;
  }
  b -= 672;
  if (b < 2304) {          // W_q -> xpb rows [0,3072), 24x96
    cvt_t_body(tile, b % 24, b / 24, 0, W_q, 0, 3072, xpb_h, 0, 768, 0, 768, 3072, false, 1.f);
    return;
  }
  b -= 2304;
  if (b < 192) {           // skip_down -> xpb rows [3072,3264), 24x8
    cvt_t_body(tile, b % 24, b / 24, 0, skip_down_W, 0, 192, xpb_h + (size_t)3072 * 768,
               0, 768, 0, 768, 192, false, 1.f);
    return;
  }
  b -= 192;
  if (b < 1728) {          // out_W -> outw, 72x24
    cvt_t_body(tile, b % 72, b / 72, 0, out_W, 0, 768, outw_h, 0, 2304, 0, 2304, 768, false, 1.f);
    return;
  }
  b -= 1728;
  if (b < 288) {           // W_re -> bsp[k][perm(n)][0:64], 2x12x12
    cvt_t_body(tile, b % 2, (b / 2) % 12, b / 24, W_re, 64L * 384, 384, bsp_h,
               384L * 320, 320, 0, 64, 384, true, 1.f);
    return;
  }
  b -= 288;
  if (b < 288) {           // W_im -> bsp[k][perm(n)][64:128]
    cvt_t_body(tile, b % 2, (b / 2) % 12, b / 24, W_im, 64L * 384, 384, bsp_h,
               384L * 320, 320, 64, 64, 384, true, 1.f);
    return;
  }
  b -= 288;
  // skip_up slice -> bsp[k][perm(n)][128:320] scaled by hs[k], 6x12x12
  int kz = b / 72;
  cvt_t_body(tile, b % 6, (b / 6) % 12, kz, skip_up_W, 384, 4608, bsp_h,
             384L * 320, 320, 128, 192, 384, true, hs[kz]);
}

// ---------------------------------------------------------------------------
// MFMA fp16 GEMM: dbuf LDS, raw barriers + fine vmcnt, XOR(row>>1) swizzle.
// EPI=0: f32 store. ATOMIC=1: 1D XCD-swizzled grid (gx,gy,nsplit), atomicAdd.
// EPI=1: spec GEMM: A from split source (Ah per-k 128-stride k<128, A2 shared
//        192-stride k>=128); fused val/gate SiLU -> YH.
// EPI=2: merged x-projection: col<3072 -> QH fp16 (q); [3072,3264) -> YH fp16
//        (lat); [3328,3328+780) -> C f32 (z_pre); else skip.
// ---------------------------------------------------------------------------
template <int ATOMIC, int EPI>
__global__ __launch_bounds__(256)
void mfma_gemm_kernel(const _Float16* __restrict__ Ah, const _Float16* __restrict__ Bh,
                      float* __restrict__ C,
                      int Kd, int Nact,
                      long strideA, long strideB, long strideC,
                      const _Float16* __restrict__ A2, _Float16* __restrict__ YH,
                      _Float16* __restrict__ QH, int gx, int gy, int nsplit) {
  __shared__ __align__(16) _Float16 sA[2][128 * 32];
  __shared__ __align__(16) _Float16 sB[2][128 * 32];
  int bx, by, kz, kbeg, kend;
  if (ATOMIC) {
    // XCD-aware swizzle: pin A-slices (y,z) to one XCD's L2, x innermost
    int bid = blockIdx.x;
    int xcd = bid & 7, s = bid >> 3;
    bx = s % gx;
    int yz = s / gx;
    int p = xcd + 8 * yz;
    by = p % gy;
    int zz = p / gy;
    kz = 0;
    int len = Kd / nsplit;
    kbeg = zz * len;
    kend = kbeg + len;
  } else {
    bx = blockIdx.x; by = blockIdx.y; kz = blockIdx.z;
    kbeg = 0; kend = Kd;
  }
  const _Float16* A0 = Ah + (size_t)kz * strideA;
  const _Float16* B0 = Bh + (size_t)kz * strideB;
  float* Cb = C + (size_t)kz * strideC;
  const int bm0 = by * 128;
  const int bn0 = bx * 128;
  const int tid = threadIdx.x;
  const int wave = tid >> 6, lane = tid & 63;
  const int m16 = lane & 15, quad = lane >> 4;
  const int wr = (wave & 1) * 64, wc = (wave >> 1) * 64;

  f32x4 acc[4][4];
#pragma unroll
  for (int i = 0; i < 4; ++i)
#pragma unroll
    for (int j = 0; j < 4; ++j) acc[i][j] = (f32x4){0.f, 0.f, 0.f, 0.f};

  const int lin = tid * 8;                 // LDS slot (halfs), 16 B per thread
  const int lrow = lin >> 5;               // 0..63
  const int lblk = (lin >> 3) & 3;         // 16-B block within row
  const int csw = ((lblk ^ ((lrow >> 1) & 3)) << 3);   // XOR bank swizzle

  auto stage = [&](int k0, int kb) {
    if constexpr (EPI == 1) {
      if (k0 < 128) {
        const _Float16* gA = A0 + (size_t)(bm0 + lrow) * 128 + (k0 + csw);
        async16(gA, &sA[kb][lin]);
        async16(gA + (size_t)64 * 128, &sA[kb][lin + 2048]);
      } else {
        const _Float16* gA = A2 + (size_t)(bm0 + lrow) * 192 + (k0 - 128 + csw);
        async16(gA, &sA[kb][lin]);
        async16(gA + (size_t)64 * 192, &sA[kb][lin + 2048]);
      }
    } else {
      const _Float16* gA = A0 + (size_t)(bm0 + lrow) * Kd + (k0 + csw);
      async16(gA, &sA[kb][lin]);
      async16(gA + (size_t)64 * Kd, &sA[kb][lin + 2048]);
    }
    const _Float16* gB = B0 + (size_t)(bn0 + lrow) * Kd + (k0 + csw);
    async16(gB, &sB[kb][lin]);
    async16(gB + (size_t)64 * Kd, &sB[kb][lin + 2048]);
  };

  const int niter = (kend - kbeg) / 32;
  stage(kbeg, 0);
  if (niter > 1) stage(kbeg + 32, 1);

  for (int it = 0; it < niter; ++it) {
    if (it == niter - 1)
      __builtin_amdgcn_s_waitcnt(0x0F70);   // vmcnt(0)
    else
      __builtin_amdgcn_s_waitcnt(0x0F74);   // vmcnt(4)
    __builtin_amdgcn_s_barrier();
    asm volatile("" ::: "memory");
    const int kb = it & 1;
    half8 a0[4], b0[4];
#pragma unroll
    for (int i = 0; i < 4; ++i) {
      const int rA = wr + i * 16 + m16;
      a0[i] = *(const half8*)&sA[kb][rA * 32 + ((quad ^ ((rA >> 1) & 3)) << 3)];
    }
#pragma unroll
    for (int j = 0; j < 4; ++j) {
      const int rB = wc + j * 16 + m16;
      b0[j] = *(const half8*)&sB[kb][rB * 32 + ((quad ^ ((rB >> 1) & 3)) << 3)];
    }
#pragma unroll
    for (int i = 0; i < 4; ++i)
#pragma unroll
      for (int j = 0; j < 4; ++j)
        acc[i][j] = __builtin_amdgcn_mfma_f32_16x16x32_f16(a0[i], b0[j], acc[i][j], 0, 0, 0);
    asm volatile("" ::: "memory");
    __builtin_amdgcn_s_barrier();
    asm volatile("" ::: "memory");
    if (it + 2 < niter) stage(kbeg + (it + 2) * 32, kb);
  }

  // epilogues (C/D layout: col=lane&15, row=quad*4+reg)
  if constexpr (EPI == 1) {
#pragma unroll
    for (int i = 0; i < 4; ++i) {
      const int row0 = bm0 + wr + i * 16 + quad * 4;
#pragma unroll
      for (int j = 0; j < 4; j += 2) {
        const int colv = bn0 + wc + j * 16 + m16;
        const int jout = (colv >> 5) * 16 + m16;
#pragma unroll
        for (int r = 0; r < 4; ++r) {
          float val = acc[i][j][r];
          float g = acc[i][j + 1][r];
          float s = g / (1.f + __expf(-g));
          YH[(size_t)(row0 + r) * 2304 + kz * 192 + jout] = (_Float16)(val * s);
        }
      }
    }
  } else if constexpr (EPI == 2) {
#pragma unroll
    for (int i = 0; i < 4; ++i) {
      const int row0 = bm0 + wr + i * 16 + quad * 4;
#pragma unroll
      for (int j = 0; j < 4; ++j) {
        const int col = bn0 + wc + j * 16 + m16;
        if (col < 3072) {
#pragma unroll
          for (int r = 0; r < 4; ++r)
            QH[(size_t)(row0 + r) * QST_ + col] = (_Float16)acc[i][j][r];
        } else if (col < 3264) {
          const int jj = col - 3072;
#pragma unroll
          for (int r = 0; r < 4; ++r)
            YH[(size_t)(row0 + r) * 192 + jj] = (_Float16)acc[i][j][r];
        } else if (col >= 3328 && col < 3328 + ZC_) {
          const int wz = col - 3328;
#pragma unroll
          for (int r = 0; r < 4; ++r)
            Cb[(size_t)(row0 + r) * ZC_ + wz] = acc[i][j][r];
        }
      }
    }
  } else {
#pragma unroll
    for (int i = 0; i < 4; ++i) {
      const int row0 = bm0 + wr + i * 16 + quad * 4;
#pragma unroll
      for (int j = 0; j < 4; ++j) {
        const int col = bn0 + wc + j * 16 + m16;
        if (col < Nact) {
#pragma unroll
          for (int r = 0; r < 4; ++r) {
            if (ATOMIC)
              atomicAdd(&Cb[(size_t)(row0 + r) * Nact + col], acc[i][j][r]);
            else
              Cb[(size_t)(row0 + r) * Nact + col] = acc[i][j][r];
          }
        }
      }
    }
  }
}

// ---------------------------------------------------------------------------
// Scan pass A with fused causal conv (sliding 4-tap window over z_pre)
// ---------------------------------------------------------------------------
__global__ void pass_a_kernel(const float* __restrict__ zp,
                              const float* __restrict__ ck,
                              const float* __restrict__ theta_tab,
                              const float* __restrict__ score_scale,
                              const float* __restrict__ tanh_scale,
                              const float* __restrict__ slopes_sp,
                              float* __restrict__ csums) {
  const int c = blockIdx.x, k = blockIdx.y, b = blockIdx.z;
  const int tid = threadIdx.x;
  const int m = tid & 3, h = tid >> 2;
  const int chk = k * H_ + h;
  const int chs = 768 + k;
  const float theta_v = theta_tab[chk * M_ + m];
  const float ts = tanh_scale[k], ss = score_scale[k], slope = slopes_sp[k];
  float ckv[4], cks[4];
#pragma unroll
  for (int w = 0; w < 4; ++w) { ckv[w] = ck[w * ZC_ + chk]; cks[w] = ck[w * ZC_ + chs]; }
  const int l0 = c * LC_;
  float zk3 = 0.f, zk2 = 0.f, zk1 = 0.f, zs3 = 0.f, zs2 = 0.f, zs1 = 0.f;
#pragma unroll
  for (int p = 0; p < 3; ++p) {
    int lp = l0 - 3 + p;
    if (lp >= 0) {
      size_t tp = (size_t)b * L_ + lp;
      float zk = zp[tp * ZC_ + chk], zs = zp[tp * ZC_ + chs];
      if (p == 0) { zk3 = zk; zs3 = zs; }
      else if (p == 1) { zk2 = zk; zs2 = zs; }
      else { zk1 = zk; zs1 = zs; }
    }
  }
  float sre = 0.f, sim = 0.f, dacc = 0.f;
  for (int ll = 0; ll < LC_; ++ll) {
    int l = l0 + ll;
    size_t t = (size_t)b * L_ + l;
    float zk0 = zp[t * ZC_ + chk];
    float zs0 = zp[t * ZC_ + chs];
    float kv = zk3 * ckv[0] + zk2 * ckv[1] + zk1 * ckv[2] + zk0 * ckv[3];
    float sraw = zs3 * cks[0] + zs2 * cks[1] + zs1 * cks[2] + zs0 * cks[3];
    zk3 = zk2; zk2 = zk1; zk1 = zk0;
    zs3 = zs2; zs2 = zs1; zs1 = zs0;
    float lp = fminf(fmaxf(ss * sraw, -20.f), 20.f);
    float pw = __expf(lp - slope * (float)(L_ - 1 - l));
    float ph = fast_tanh(ts * kv) * theta_v;
    float kvp = kv * pw;
    sre += kvp * __cosf(ph);
    sim += kvp * __sinf(ph);
    dacc += pw;
  }
  size_t base = (((size_t)b * K_ + k) * NC_ + c) * 513;
  if (tid == 0) csums[base] = dacc;
  csums[base + 1 + h * 4 + m] = sre;
  csums[base + 1 + 256 + h * 4 + m] = sim;
}

// ---------------------------------------------------------------------------
__global__ void pass_b_kernel(const float* __restrict__ csums,
                              float* __restrict__ cpre) {
  int bk = blockIdx.y;
  int comp = blockIdx.x * 64 + threadIdx.x;
  if (comp >= 513) return;
  float run = 0.f;
  size_t base = (size_t)bk * NC_ * 513 + comp;
  for (int c = 0; c < NC_; ++c) {
    cpre[base + (size_t)c * 513] = run;
    run += csums[base + (size_t)c * 513];
  }
}

// ---------------------------------------------------------------------------
// Scan pass C: fused conv replay, contract with fp16 q, apply ns*gate,
// write fp16 into asp2[k][t][0:128] (128-stride)
// ---------------------------------------------------------------------------
__global__ void pass_c_kernel(const float* __restrict__ zp,
                              const float* __restrict__ ck,
                              const _Float16* __restrict__ qh,
                              const float* __restrict__ theta_tab,
                              const float* __restrict__ w_tab,
                              const float* __restrict__ score_scale,
                              const float* __restrict__ tanh_scale,
                              const float* __restrict__ slopes_sp,
                              const float* __restrict__ cpre,
                              const float* __restrict__ gatelin,
                              const float* __restrict__ gate_b,
                              const float* __restrict__ ns,
                              _Float16* __restrict__ asp) {
  const int c = blockIdx.x, k = blockIdx.y, b = blockIdx.z;
  const int tid = threadIdx.x;
  const int m = tid & 3, h = tid >> 2;
  const int chk = k * H_ + h;
  const int chs = 768 + k;
  size_t base = (((size_t)b * K_ + k) * NC_ + c) * 513;
  float den = cpre[base];
  float sre = cpre[base + 1 + h * 4 + m];
  float sim = cpre[base + 1 + 256 + h * 4 + m];
  const float theta_v = theta_tab[chk * M_ + m];
  const float w = w_tab[chk * M_ + m];
  const float ts = tanh_scale[k], ss = score_scale[k], slope = slopes_sp[k];
  const float nsv = ns[chk];
  const float gb = gate_b[k];
  const int kq = k >> 1;   // NREP = 2
  float ckv[4], cks[4];
#pragma unroll
  for (int ww = 0; ww < 4; ++ww) { ckv[ww] = ck[ww * ZC_ + chk]; cks[ww] = ck[ww * ZC_ + chs]; }
  const int l0 = c * LC_;
  float zk3 = 0.f, zk2 = 0.f, zk1 = 0.f, zs3 = 0.f, zs2 = 0.f, zs1 = 0.f;
#pragma unroll
  for (int p = 0; p < 3; ++p) {
    int lp = l0 - 3 + p;
    if (lp >= 0) {
      size_t tp = (size_t)b * L_ + lp;
      float zk = zp[tp * ZC_ + chk], zs = zp[tp * ZC_ + chs];
      if (p == 0) { zk3 = zk; zs3 = zs; }
      else if (p == 1) { zk2 = zk; zs2 = zs; }
      else { zk1 = zk; zs1 = zs; }
    }
  }
  const int qidx = ((kq * H_ + h) * M_ + m) * 2;
  for (int ll = 0; ll < LC_; ++ll) {
    int l = l0 + ll;
    size_t t = (size_t)b * L_ + l;
    float zk0 = zp[t * ZC_ + chk];
    float zs0 = zp[t * ZC_ + chs];
    float kv = zk3 * ckv[0] + zk2 * ckv[1] + zk1 * ckv[2] + zk0 * ckv[3];
    float sraw = zs3 * cks[0] + zs2 * cks[1] + zs1 * cks[2] + zs0 * cks[3];
    zk3 = zk2; zk2 = zk1; zk1 = zk0;
    zs3 = zs2; zs2 = zs1; zs1 = zs0;
    float lp = fminf(fmaxf(ss * sraw, -20.f), 20.f);
    float pw = __expf(lp - slope * (float)(L_ - 1 - l));
    float ph = fast_tanh(ts * kv) * theta_v;
    float kvp = kv * pw;
    sre += kvp * __cosf(ph);
    sim += kvp * __sinf(ph);
    den += pw;
    float inv = 1.f / fmaxf(den, 1e-4f);
    float s_re = sre * inv, s_im = sim * inv;
    size_t qb = t * QST_ + qidx;
    float qr = (float)qh[qb], qi = (float)qh[qb + 1];
    float tr = (s_re * qr + s_im * qi) * w;
    float ti = (s_im * qr - s_re * qi) * w;
    tr += __shfl_xor(tr, 1); tr += __shfl_xor(tr, 2);
    ti += __shfl_xor(ti, 1); ti += __shfl_xor(ti, 2);
    if (m == 0) {
      float g = 1.f / (1.f + __expf(-(gatelin[t * K_ + k] + gb))) * nsv;
      size_t ab = ((size_t)k * NTOK_ + t) * 128;
      asp[ab + h] = (_Float16)(tr * g);
      asp[ab + 64 + h] = (_Float16)(ti * g);
    }
  }
}

// ---------------------------------------------------------------------------
extern "C" void kernel_launch(void* const* d_in, const int* in_sizes, int n_in,
                              void* d_out, int out_size, void* d_ws, size_t ws_size,
                              hipStream_t stream) {
  const float* x            = (const float*)d_in[0];
  const float* W_mem        = (const float*)d_in[1];
  const float* conv_k       = (const float*)d_in[2];
  const float* W_q          = (const float*)d_in[3];
  const float* theta_d_raw  = (const float*)d_in[4];
  const float* decay_slopes = (const float*)d_in[5];
  const float* score_scale  = (const float*)d_in[6];
  const float* tanh_scale   = (const float*)d_in[7];
  const float* W_re         = (const float*)d_in[8];
  const float* W_im         = (const float*)d_in[9];
  const float* norm_scale   = (const float*)d_in[10];
  const float* gate_W       = (const float*)d_in[11];
  const float* gate_b       = (const float*)d_in[12];
  const float* skip_down_W  = (const float*)d_in[13];
  const float* skip_up_W    = (const float*)d_in[14];
  const float* highway_scale= (const float*)d_in[15];
  const float* out_W        = (const float*)d_in[16];
  float* out = (float*)d_out;
  float* ws = (float*)d_ws;

  // ---- f32 region ----
  float* theta_tab = ws;                                  // 3072
  float* w_tab     = theta_tab + 3072;                    // 3072
  float* slopes_sp = w_tab + 3072;                        // 16
  float* z_pre     = slopes_sp + 16;                      // 3,194,880
  float* gatelin   = z_pre + (size_t)NTOK_ * ZC_;         // 49,152
  float* csums     = gatelin + (size_t)NTOK_ * K_;        // 787,968
  float* cpre      = csums + (size_t)B_ * K_ * NC_ * 513; // 787,968
  _Float16* q_h    = (_Float16*)(cpre + (size_t)B_ * K_ * NC_ * 513); // 4096x3072
  _Float16* y_h    = q_h + (size_t)NTOK_ * QST_;          // 4096x2304
  float* f32_end   = (float*)(y_h + (size_t)NTOK_ * 2304);

  // ---- fp16 region ----
  _Float16* fp = (_Float16*)f32_end;
  _Float16* x_h    = fp;                fp += (size_t)NTOK_ * D_;
  _Float16* xpb_h  = fp;                fp += (size_t)XPN_ * 768;   // merged proj B
  _Float16* outw_h = fp;                fp += (size_t)768 * 2304;
  _Float16* asp2_h = fp;                fp += (size_t)K_ * NTOK_ * 128;
  _Float16* bsp_h  = fp;                fp += (size_t)K_ * 384 * 320;
  _Float16* lat_h  = fp;                fp += (size_t)NTOK_ * 192;

  // zero split-K atomic target (out only, 3.1M floats)
  zero1_kernel<<<(int)(((size_t)NTOK_ * D_ + 255) / 256), 256, 0, stream>>>(out, (size_t)NTOK_ * D_);
  precomp_kernel<<<3, 256, 0, stream>>>(theta_d_raw, decay_slopes, theta_tab, w_tab, slopes_sp);

  // conversions
  cvt_h_kernel<<<(NTOK_ * D_ + 255) / 256, 256, 0, stream>>>(x, x_h, NTOK_ * D_);
  cvtw_kernel<<<6336, 256, 0, stream>>>(W_mem, W_q, skip_down_W, out_W, W_re, W_im, skip_up_W,
                                        highway_scale, xpb_h, outw_h, bsp_h);

  // merged x-projection: q (fp16) + lat (fp16) + z_pre (f32) in ONE dispatch
  mfma_gemm_kernel<0, 2><<<dim3(33, 32, 1), 256, 0, stream>>>(x_h, xpb_h, z_pre,
                                                              768, XPN_, 0, 0, 0,
                                                              nullptr, lat_h, q_h, 0, 0, 0);
  // gatelin = x @ gate_W
  gate_kernel<<<NTOK_ / 4, 256, 0, stream>>>(x, gate_W, gatelin);

  // chunked scan (f32) with fused causal conv
  pass_a_kernel<<<dim3(NC_, K_, B_), 256, 0, stream>>>(z_pre, conv_k, theta_tab, score_scale,
                                                       tanh_scale, slopes_sp, csums);
  pass_b_kernel<<<dim3(9, B_ * K_), 64, 0, stream>>>(csums, cpre);
  pass_c_kernel<<<dim3(NC_, K_, B_), 256, 0, stream>>>(z_pre, conv_k, q_h, theta_tab, w_tab,
                                                       score_scale, tanh_scale, slopes_sp, cpre,
                                                       gatelin, gate_b, norm_scale, asp2_h);

  // batched spec GEMM (A = [asp2 per-k | lat_h shared], hs folded into bsp)
  // with fused SiLU -> y_h fp16
  mfma_gemm_kernel<0, 1><<<dim3(3, 32, K_), 256, 0, stream>>>(asp2_h, bsp_h, nullptr,
                                                              320, 384,
                                                              (long)NTOK_ * 128, 384L * 320, 0,
                                                              lat_h, y_h, nullptr, 0, 0, 0);
  // out += y @ out_W  (split-K=4, atomic, XCD-swizzled 1D grid)
  mfma_gemm_kernel<1, 0><<<768, 256, 0, stream>>>(y_h, outw_h, out,
                                                  2304, 768, 0, 0, 0,
                                                  nullptr, nullptr, nullptr, 6, 32, 4);
}